// Round 6
// baseline (574.721 us; speedup 1.0000x reference)
//
#include <hip/hip_runtime.h>

#define S     2048
#define D     64
#define NH    12
#define NB    2
#define NBH   (NB*NH)       // 24
#define OUTSZ ((size_t)NBH*S*D)

#define BQ    32
#define QT    (S/BQ)        // 64
#define NBLK  (NBH*QT)      // 1536

// workspace layout (bytes)
#define KCAT_OFF  0
#define KCAT_SZ   ((size_t)NBH*S*128*2)        // 12582912
#define VT_OFF    (KCAT_OFF + KCAT_SZ)
#define VT_SZ     ((size_t)2*NBH*D*S*2)        // 12582912
#define MT_OFF    (VT_OFF + VT_SZ)
#define MT_SZ     ((size_t)NB*S*S)             // 8388608
#define WS_NEED   (MT_OFF + MT_SZ)             // 33554432  (tier-2 minimum)
#define E_OFF     WS_NEED
#define E_SZ      ((size_t)NBH*S*S*2)          // 201326592
#define LINV_OFF  (E_OFF + E_SZ)
#define LINV_SZ   ((size_t)NBH*S*4)            // 196608
#define WS_FULL   (LINV_OFF + LINV_SZ)         // 235077632 (tier-1)

typedef __attribute__((ext_vector_type(8))) short short8;
typedef __attribute__((ext_vector_type(4))) short s4v;
typedef __attribute__((ext_vector_type(4))) float f32x4;

__device__ __forceinline__ unsigned short f2bf(float x){
  unsigned u = __builtin_bit_cast(unsigned, x);
  u += 0x7fffu + ((u >> 16) & 1u);       // RTNE
  return (unsigned short)(u >> 16);
}
__device__ __forceinline__ float bf2f(unsigned short h){
  unsigned u = ((unsigned)h) << 16;
  return __builtin_bit_cast(float, u);
}
__device__ __forceinline__ short8 pack8(const float4& a, const float4& b, float sc){
  short8 r;
  r[0]=(short)f2bf(a.x*sc); r[1]=(short)f2bf(a.y*sc);
  r[2]=(short)f2bf(a.z*sc); r[3]=(short)f2bf(a.w*sc);
  r[4]=(short)f2bf(b.x*sc); r[5]=(short)f2bf(b.y*sc);
  r[6]=(short)f2bf(b.z*sc); r[7]=(short)f2bf(b.w*sc);
  return r;
}
__device__ __forceinline__ int eoff(int row, int key){
  return ((row << 12) | (key << 1)) ^ ((row & 7) << 4);
}

// ---------------- conversion pre-kernels (proven) ----------------

__global__ __launch_bounds__(256) void conv_k(const float* __restrict__ kr,
                                              const float* __restrict__ ki,
                                              unsigned short* __restrict__ kcat){
  int idx = blockIdx.x*256 + threadIdx.x;
  int d8  = (idx & 15) * 8;
  int ri  = idx >> 4;
  const float* src = (d8 < 64 ? kr + (size_t)ri*64 + d8 : ki + (size_t)ri*64 + (d8-64));
  float4 a = *(const float4*)(src);
  float4 b = *(const float4*)(src + 4);
  *(short8*)(kcat + (size_t)ri*128 + d8) = pack8(a, b, 1.f);
}

__global__ __launch_bounds__(256) void conv_v(const float* __restrict__ vr,
                                              const float* __restrict__ vi,
                                              unsigned short* __restrict__ vt){
  __shared__ unsigned short tile[64][65];
  int bid = blockIdx.x;
  int ri  = bid / (NBH*32);
  int rem = bid % (NBH*32);
  int bh  = rem / 32;
  int s0  = (rem % 32) * 64;
  const float* vp = (ri ? vi : vr) + (size_t)bh*S*D;
  int t = threadIdx.x;
  #pragma unroll
  for (int it = 0; it < 4; it++){
    int row = (t >> 4) + it*16;
    int c4  = (t & 15) * 4;
    float4 v = *(const float4*)(vp + (size_t)(s0+row)*D + c4);
    tile[c4+0][row] = f2bf(v.x);
    tile[c4+1][row] = f2bf(v.y);
    tile[c4+2][row] = f2bf(v.z);
    tile[c4+3][row] = f2bf(v.w);
  }
  __syncthreads();
  unsigned short* dst = vt + ((size_t)(ri*NBH + bh) * D) * S;
  #pragma unroll
  for (int it = 0; it < 4; it++){
    int d  = (t >> 4) + it*16;
    int s4 = (t & 15) * 4;
    s4v o;
    o[0]=(short)tile[d][s4+0]; o[1]=(short)tile[d][s4+1];
    o[2]=(short)tile[d][s4+2]; o[3]=(short)tile[d][s4+3];
    *(s4v*)(dst + (size_t)d*S + s0 + s4) = o;
  }
}

__global__ __launch_bounds__(256) void conv_m(const int* __restrict__ mask,
                                              unsigned char* __restrict__ mt){
  __shared__ unsigned char tile[64][68];
  int bid = blockIdx.x;
  int b   = bid / 1024;
  int rem = bid % 1024;
  int r0  = (rem / 32) * 64;
  int k0  = (rem % 32) * 64;
  int t = threadIdx.x;
  const int* mp = mask + (size_t)b*S*S;
  #pragma unroll
  for (int it = 0; it < 4; it++){
    int row = (t >> 4) + it*16;
    int c4  = (t & 15) * 4;
    int4 v = *(const int4*)(mp + (size_t)(r0+row)*S + k0 + c4);
    tile[c4+0][row] = (unsigned char)v.x;
    tile[c4+1][row] = (unsigned char)v.y;
    tile[c4+2][row] = (unsigned char)v.z;
    tile[c4+3][row] = (unsigned char)v.w;
  }
  __syncthreads();
  unsigned char* dst = mt + (size_t)b*S*S;
  #pragma unroll
  for (int it = 0; it < 4; it++){
    int k  = (t >> 4) + it*16;
    int r4 = (t & 15) * 4;
    unsigned u = (unsigned)tile[k][r4+0] | ((unsigned)tile[k][r4+1]<<8)
               | ((unsigned)tile[k][r4+2]<<16) | ((unsigned)tile[k][r4+3]<<24);
    *(unsigned*)(dst + (size_t)(k0+k)*S + r0 + r4) = u;
  }
}

// ---------------- tier-1 kernel A: scores -> e(bf16) + l_inv ----------------
// key(col) = base + 2*col (+1): lane holds two ADJACENT keys -> packed 4B e-stores.

__global__ __launch_bounds__(512) void score_kernel(
    const float* __restrict__ q_real, const float* __restrict__ q_imag,
    const unsigned short* __restrict__ kcat,
    const unsigned char*  __restrict__ mt,
    unsigned short* __restrict__ e_ws, float* __restrict__ linv_ws)
{
  __shared__ float l_red[8*BQ];

  int bid = blockIdx.x;
  int swz = (bid & 7) * (NBLK/8) + (bid >> 3);
  int bh    = swz / QT;
  int qt    = swz % QT;
  int b0    = bh / NH;
  int qbase = qt * BQ;

  int tid  = threadIdx.x;
  int w    = tid >> 6;       // 0..7
  int lane = tid & 63;
  int col  = lane & 15;
  int kg   = lane >> 4;

  const size_t bhSD = (size_t)bh * S * D;

  // Q fragments: A_r = [qr,qi]/8, A_i = [qi,-qr]/8 (K=128 over 4 chunks of 32)
  short8 a_r[2][4], a_i[2][4];
  #pragma unroll
  for (int m = 0; m < 2; m++){
    const float* qrp = q_real + bhSD + (size_t)(qbase + m*16 + col) * D;
    const float* qip = q_imag + bhSD + (size_t)(qbase + m*16 + col) * D;
    #pragma unroll
    for (int h = 0; h < 2; h++){
      int d0 = h*32 + kg*8;
      float4 r0 = *(const float4*)(qrp + d0);
      float4 r1 = *(const float4*)(qrp + d0 + 4);
      float4 i0 = *(const float4*)(qip + d0);
      float4 i1 = *(const float4*)(qip + d0 + 4);
      a_r[m][h]   = pack8(r0, r1,  0.125f);
      a_r[m][2+h] = pack8(i0, i1,  0.125f);
      a_i[m][h]   = a_r[m][2+h];
      a_i[m][2+h] = pack8(r0, r1, -0.125f);
    }
  }

  float lsum[2][4] = {{0.f,0.f,0.f,0.f},{0.f,0.f,0.f,0.f}};
  unsigned short* estripe = e_ws + ((size_t)bh*S + qbase) * S;
  const unsigned char* mbase = mt + (size_t)b0*S*S;

  for (int t = 0; t < 8; t++){
    int base = w*256 + t*32;
    int keyA = base + 2*col;            // even
    const unsigned short* krA = kcat + ((size_t)bh*S + keyA) * 128;
    short8 bvA[4], bvB[4];
    #pragma unroll
    for (int kc = 0; kc < 4; kc++){
      bvA[kc] = *(const short8*)(krA + kc*32 + kg*8);
      bvB[kc] = *(const short8*)(krA + 128 + kc*32 + kg*8);
    }
    const unsigned char* mA = mbase + (size_t)keyA*S + qbase + kg*4;
    unsigned umA0 = *(const unsigned*)(mA);
    unsigned umA1 = *(const unsigned*)(mA + 16);
    unsigned umB0 = *(const unsigned*)(mA + S);
    unsigned umB1 = *(const unsigned*)(mA + S + 16);

    f32x4 aAr[2], aAi[2], aBr[2], aBi[2];
    #pragma unroll
    for (int m = 0; m < 2; m++){
      aAr[m] = (f32x4)(0.f); aAi[m] = (f32x4)(0.f);
      aBr[m] = (f32x4)(0.f); aBi[m] = (f32x4)(0.f);
    }
    #pragma unroll
    for (int m = 0; m < 2; m++)
      #pragma unroll
      for (int kc = 0; kc < 4; kc++){
        aAr[m] = __builtin_amdgcn_mfma_f32_16x16x32_bf16(a_r[m][kc], bvA[kc], aAr[m], 0, 0, 0);
        aAi[m] = __builtin_amdgcn_mfma_f32_16x16x32_bf16(a_i[m][kc], bvA[kc], aAi[m], 0, 0, 0);
        aBr[m] = __builtin_amdgcn_mfma_f32_16x16x32_bf16(a_r[m][kc], bvB[kc], aBr[m], 0, 0, 0);
        aBi[m] = __builtin_amdgcn_mfma_f32_16x16x32_bf16(a_i[m][kc], bvB[kc], aBi[m], 0, 0, 0);
      }
    #pragma unroll
    for (int m = 0; m < 2; m++){
      unsigned umA = m ? umA1 : umA0;
      unsigned umB = m ? umB1 : umB0;
      #pragma unroll
      for (int r = 0; r < 4; r++){
        float arA = aAr[m][r], aiA = aAi[m][r];
        float sA  = sqrtf(arA*arA + aiA*aiA);
        float eA  = ((umA >> (8*r)) & 1u) ? __expf(sA) : 0.f;
        float arB = aBr[m][r], aiB = aBi[m][r];
        float sB  = sqrtf(arB*arB + aiB*aiB);
        float eB  = ((umB >> (8*r)) & 1u) ? __expf(sB) : 0.f;
        lsum[m][r] += eA + eB;
        unsigned pk = (unsigned)f2bf(eA) | ((unsigned)f2bf(eB) << 16);
        *(unsigned*)(estripe + (size_t)(m*16 + kg*4 + r) * S + keyA) = pk;
      }
    }
  }

  #pragma unroll
  for (int m = 0; m < 2; m++)
    #pragma unroll
    for (int r = 0; r < 4; r++){
      float v = lsum[m][r];
      v += __shfl_xor(v, 1); v += __shfl_xor(v, 2);
      v += __shfl_xor(v, 4); v += __shfl_xor(v, 8);
      lsum[m][r] = v;
    }
  if (col == 0){
    #pragma unroll
    for (int m = 0; m < 2; m++)
      #pragma unroll
      for (int r = 0; r < 4; r++)
        l_red[w*BQ + m*16 + kg*4 + r] = lsum[m][r];
  }
  __syncthreads();
  if (tid < BQ){
    float t = 0.f;
    #pragma unroll
    for (int ww = 0; ww < 8; ww++) t += l_red[ww*BQ + tid];
    linv_ws[(size_t)bh*S + qbase + tid] = 1.f / t;
  }
}

// ---------------- tier-1 kernel B: PV + in-loop attn write, zero LDS ----------

__global__ __launch_bounds__(512) void pv_kernel(
    const unsigned short* __restrict__ e_ws,
    const unsigned short* __restrict__ vt,
    const float* __restrict__ linv_ws,
    float* __restrict__ out)
{
  int bid = blockIdx.x;
  int swz = (bid & 7) * (NBLK/8) + (bid >> 3);
  int bh    = swz / QT;
  int qt    = swz % QT;
  int qbase = qt * BQ;

  int tid  = threadIdx.x;
  int w    = tid >> 6;       // 0..7
  int lane = tid & 63;
  int col  = lane & 15;
  int kg   = lane >> 4;

  const size_t bhSD = (size_t)bh * S * D;
  const float* linv = linv_ws + (size_t)bh*S + qbase;
  const unsigned short* estripe = e_ws + ((size_t)bh*S + qbase) * S;
  float* attnp = out + 2*OUTSZ + (size_t)bh*S*S + (size_t)qbase*S;

  int ri    = w >> 2;
  int dbase = (w & 3) * 16;
  const unsigned short* vrow = vt + ((size_t)(ri*NBH + bh) * D + dbase + col) * S;
  const unsigned short* e0 = estripe + (size_t)col * S;        // A row = col (m=0)
  const unsigned short* e1 = e0 + (size_t)16 * S;              // m=1
  float invA = linv[col];
  float invB = linv[16 + col];
  f32x4 acc0 = (f32x4)(0.f), acc1 = (f32x4)(0.f);

  #pragma unroll 4
  for (int c = 0; c < 64; c++){
    int k0 = c*32 + kg*8;
    short8 bv = *(const short8*)(vrow + k0);
    short8 a0 = *(const short8*)(e0 + k0);
    short8 a1 = *(const short8*)(e1 + k0);
    acc0 = __builtin_amdgcn_mfma_f32_16x16x32_bf16(a0, bv, acc0, 0, 0, 0);
    acc1 = __builtin_amdgcn_mfma_f32_16x16x32_bf16(a1, bv, acc1, 0, 0, 0);
    if ((c >> 3) == w){
      // this wave writes attn for keys [c*32, c*32+32): rows col and 16+col
      float4 o0, o1;
      float* p0 = attnp + (size_t)col*S + k0;
      o0.x = bf2f((unsigned short)a0[0]) * invA;
      o0.y = bf2f((unsigned short)a0[1]) * invA;
      o0.z = bf2f((unsigned short)a0[2]) * invA;
      o0.w = bf2f((unsigned short)a0[3]) * invA;
      o1.x = bf2f((unsigned short)a0[4]) * invA;
      o1.y = bf2f((unsigned short)a0[5]) * invA;
      o1.z = bf2f((unsigned short)a0[6]) * invA;
      o1.w = bf2f((unsigned short)a0[7]) * invA;
      *(float4*)(p0)     = o0;
      *(float4*)(p0 + 4) = o1;
      float* p1 = attnp + (size_t)(16 + col)*S + k0;
      o0.x = bf2f((unsigned short)a1[0]) * invB;
      o0.y = bf2f((unsigned short)a1[1]) * invB;
      o0.z = bf2f((unsigned short)a1[2]) * invB;
      o0.w = bf2f((unsigned short)a1[3]) * invB;
      o1.x = bf2f((unsigned short)a1[4]) * invB;
      o1.y = bf2f((unsigned short)a1[5]) * invB;
      o1.z = bf2f((unsigned short)a1[6]) * invB;
      o1.w = bf2f((unsigned short)a1[7]) * invB;
      *(float4*)(p1)     = o0;
      *(float4*)(p1 + 4) = o1;
    }
  }

  float* outp = out + (ri ? OUTSZ : 0) + bhSD;
  #pragma unroll
  for (int r = 0; r < 4; r++){
    int row0 = kg*4 + r;
    outp[(size_t)(qbase + row0) * D + dbase + col]      = acc0[r] * linv[row0];
    outp[(size_t)(qbase + 16 + row0) * D + dbase + col] = acc1[r] * linv[16 + row0];
  }
}

// ---------------- tier-2: round-3 fused kernel (434 us, proven) ----------------

__global__ __launch_bounds__(1024) void cattn_fused(
    const float* __restrict__ q_real, const float* __restrict__ q_imag,
    const unsigned short* __restrict__ kcat,
    const unsigned short* __restrict__ vt,
    const unsigned char*  __restrict__ mt,
    float* __restrict__ out)
{
  extern __shared__ __align__(16) char lds[];
  float* l_lds = (float*)(lds + (size_t)BQ*S*2);
  float* l_inv = l_lds + 16*BQ;

  int bid = blockIdx.x;
  int swz = (bid & 7) * (NBLK/8) + (bid >> 3);
  int bh    = swz / QT;
  int qt    = swz % QT;
  int b0    = bh / NH;
  int qbase = qt * BQ;

  int tid  = threadIdx.x;
  int w    = tid >> 6;
  int lane = tid & 63;
  int col  = lane & 15;
  int kg   = lane >> 4;

  const size_t bhSD = (size_t)bh * S * D;

  short8 a_r[2][4], a_i[2][4];
  #pragma unroll
  for (int m = 0; m < 2; m++){
    const float* qrp = q_real + bhSD + (size_t)(qbase + m*16 + col) * D;
    const float* qip = q_imag + bhSD + (size_t)(qbase + m*16 + col) * D;
    #pragma unroll
    for (int h = 0; h < 2; h++){
      int d0 = h*32 + kg*8;
      float4 r0 = *(const float4*)(qrp + d0);
      float4 r1 = *(const float4*)(qrp + d0 + 4);
      float4 i0 = *(const float4*)(qip + d0);
      float4 i1 = *(const float4*)(qip + d0 + 4);
      a_r[m][h]   = pack8(r0, r1,  0.125f);
      a_r[m][2+h] = pack8(i0, i1,  0.125f);
      a_i[m][h]   = a_r[m][2+h];
      a_i[m][2+h] = pack8(r0, r1, -0.125f);
    }
  }

  float lsum[2][4] = {{0.f,0.f,0.f,0.f},{0.f,0.f,0.f,0.f}};

  for (int t = 0; t < 8; t++){
    int key = w*128 + t*16 + col;
    const unsigned short* krow = kcat + ((size_t)bh*S + key) * 128;
    short8 bv[4];
    #pragma unroll
    for (int kc = 0; kc < 4; kc++)
      bv[kc] = *(const short8*)(krow + kc*32 + kg*8);

    const unsigned char* mrow = mt + (size_t)b0*S*S + (size_t)key*S + qbase;
    unsigned um0 = *(const unsigned*)(mrow + kg*4);
    unsigned um1 = *(const unsigned*)(mrow + 16 + kg*4);

    f32x4 accr[2], acci[2];
    #pragma unroll
    for (int m = 0; m < 2; m++){ accr[m] = (f32x4)(0.f); acci[m] = (f32x4)(0.f); }
    #pragma unroll
    for (int m = 0; m < 2; m++)
      #pragma unroll
      for (int kc = 0; kc < 4; kc++){
        accr[m] = __builtin_amdgcn_mfma_f32_16x16x32_bf16(a_r[m][kc], bv[kc], accr[m], 0, 0, 0);
        acci[m] = __builtin_amdgcn_mfma_f32_16x16x32_bf16(a_i[m][kc], bv[kc], acci[m], 0, 0, 0);
      }
    #pragma unroll
    for (int m = 0; m < 2; m++){
      unsigned um = m ? um1 : um0;
      #pragma unroll
      for (int r = 0; r < 4; r++){
        float ar = accr[m][r], ai = acci[m][r];
        float s  = sqrtf(ar*ar + ai*ai);
        float ex = __expf(s);
        float e  = ((um >> (8*r)) & 1u) ? ex : 0.f;
        lsum[m][r] += e;
        *(unsigned short*)(lds + eoff(m*16 + kg*4 + r, key)) = f2bf(e);
      }
    }
  }

  #pragma unroll
  for (int m = 0; m < 2; m++)
    #pragma unroll
    for (int r = 0; r < 4; r++){
      float v = lsum[m][r];
      v += __shfl_xor(v, 1); v += __shfl_xor(v, 2);
      v += __shfl_xor(v, 4); v += __shfl_xor(v, 8);
      lsum[m][r] = v;
    }
  if (col == 0){
    #pragma unroll
    for (int m = 0; m < 2; m++)
      #pragma unroll
      for (int r = 0; r < 4; r++)
        l_lds[w*BQ + m*16 + kg*4 + r] = lsum[m][r];
  }
  __syncthreads();
  if (tid < BQ){
    float t = 0.f;
    #pragma unroll
    for (int ww = 0; ww < 16; ww++) t += l_lds[ww*BQ + tid];
    l_inv[tid] = 1.f / t;
  }
  __syncthreads();

  {
    int m     = w & 1;
    int dbase = ((w >> 1) & 3) * 16;
    int ri    = w >> 3;
    const unsigned short* vrow = vt + ((size_t)(ri*NBH + bh) * D + dbase + col) * S;
    f32x4 acc = (f32x4)(0.f);
    for (int c = 0; c < 64; c++){
      int k0 = c*32 + kg*8;
      short8 bv = *(const short8*)(vrow + k0);
      short8 av = *(const short8*)(lds + eoff(m*16 + col, k0));
      acc = __builtin_amdgcn_mfma_f32_16x16x32_bf16(av, bv, acc, 0, 0, 0);
    }
    float* outp = out + (ri ? OUTSZ : 0) + bhSD;
    #pragma unroll
    for (int r = 0; r < 4; r++){
      int row = m*16 + kg*4 + r;
      outp[(size_t)(qbase + row) * D + dbase + col] = acc[r] * l_inv[row];
    }
  }

  {
    float* attnp = out + 2*OUTSZ + (size_t)bh*S*S + (size_t)qbase*S;
    #pragma unroll
    for (int g = 0; g < 8; g++){
      int flat = g*8192 + tid*8;
      int row  = flat >> 11;
      int k    = flat & 2047;
      short8 ev = *(const short8*)(lds + eoff(row, k));
      float inv = l_inv[row];
      float4 o0, o1;
      o0.x = bf2f((unsigned short)ev[0]) * inv;
      o0.y = bf2f((unsigned short)ev[1]) * inv;
      o0.z = bf2f((unsigned short)ev[2]) * inv;
      o0.w = bf2f((unsigned short)ev[3]) * inv;
      o1.x = bf2f((unsigned short)ev[4]) * inv;
      o1.y = bf2f((unsigned short)ev[5]) * inv;
      o1.z = bf2f((unsigned short)ev[6]) * inv;
      o1.w = bf2f((unsigned short)ev[7]) * inv;
      *(float4*)(attnp + (size_t)row*S + k)     = o0;
      *(float4*)(attnp + (size_t)row*S + k + 4) = o1;
    }
  }
}

// ---------------- tier-3: no-workspace fallback (round-2 kernel) ----------------

__global__ __launch_bounds__(512) void cattn_kernel(
    const float* __restrict__ q_real, const float* __restrict__ q_imag,
    const float* __restrict__ k_real, const float* __restrict__ k_imag,
    const float* __restrict__ v_real, const float* __restrict__ v_imag,
    const int*   __restrict__ mask,   float* __restrict__ out)
{
  extern __shared__ __align__(16) char lds[];
  float* l_lds = (float*)(lds + (size_t)BQ*S*2);
  float* l_inv = l_lds + 8*BQ;

  int bid = blockIdx.x;
  int swz = (bid & 7) * (NBLK/8) + (bid >> 3);
  int bh    = swz / QT;
  int qt    = swz % QT;
  int b0    = bh / NH;
  int qbase = qt * BQ;

  int tid  = threadIdx.x;
  int w    = tid >> 6;
  int lane = tid & 63;
  int col  = lane & 15;
  int kg   = lane >> 4;

  const size_t bhSD = (size_t)bh * S * D;

  short8 a_r[2][4], a_i[2][4];
  #pragma unroll
  for (int m = 0; m < 2; m++){
    const float* qrp = q_real + bhSD + (size_t)(qbase + m*16 + col) * D;
    const float* qip = q_imag + bhSD + (size_t)(qbase + m*16 + col) * D;
    #pragma unroll
    for (int h = 0; h < 2; h++){
      int d0 = h*32 + kg*8;
      float4 r0 = *(const float4*)(qrp + d0);
      float4 r1 = *(const float4*)(qrp + d0 + 4);
      float4 i0 = *(const float4*)(qip + d0);
      float4 i1 = *(const float4*)(qip + d0 + 4);
      a_r[m][h]   = pack8(r0, r1,  0.125f);
      a_r[m][2+h] = pack8(i0, i1,  0.125f);
      a_i[m][h]   = a_r[m][2+h];
      a_i[m][2+h] = pack8(r0, r1, -0.125f);
    }
  }

  float lsum[2][4] = {{0.f,0.f,0.f,0.f},{0.f,0.f,0.f,0.f}};
  const int* mrow = mask + (size_t)b0 * S * S;

  for (int t = 0; t < 16; t++){
    int key = w*256 + t*16 + col;
    const float* krp = k_real + bhSD + (size_t)key * D;
    const float* kip = k_imag + bhSD + (size_t)key * D;
    short8 bv[4];
    #pragma unroll
    for (int h = 0; h < 2; h++){
      int d0 = h*32 + kg*8;
      float4 r0 = *(const float4*)(krp + d0);
      float4 r1 = *(const float4*)(krp + d0 + 4);
      float4 i0 = *(const float4*)(kip + d0);
      float4 i1 = *(const float4*)(kip + d0 + 4);
      bv[h]   = pack8(r0, r1, 1.f);
      bv[2+h] = pack8(i0, i1, 1.f);
    }
    f32x4 accr[2], acci[2];
    #pragma unroll
    for (int m = 0; m < 2; m++){ accr[m] = (f32x4)(0.f); acci[m] = (f32x4)(0.f); }
    #pragma unroll
    for (int m = 0; m < 2; m++)
      #pragma unroll
      for (int kc = 0; kc < 4; kc++){
        accr[m] = __builtin_amdgcn_mfma_f32_16x16x32_bf16(a_r[m][kc], bv[kc], accr[m], 0, 0, 0);
        acci[m] = __builtin_amdgcn_mfma_f32_16x16x32_bf16(a_i[m][kc], bv[kc], acci[m], 0, 0, 0);
      }
    #pragma unroll
    for (int m = 0; m < 2; m++){
      int qrow_g = qbase + m*16 + kg*4;
      #pragma unroll
      for (int r = 0; r < 4; r++){
        float ar = accr[m][r], ai = acci[m][r];
        float s  = sqrtf(ar*ar + ai*ai);
        int  mv  = mrow[(size_t)(qrow_g + r) * S + key];
        float ex = __expf(s);
        float e  = mv ? ex : 0.f;
        lsum[m][r] += e;
        *(unsigned short*)(lds + eoff(m*16 + kg*4 + r, key)) = f2bf(e);
      }
    }
  }

  #pragma unroll
  for (int m = 0; m < 2; m++)
    #pragma unroll
    for (int r = 0; r < 4; r++){
      float v = lsum[m][r];
      v += __shfl_xor(v, 1); v += __shfl_xor(v, 2);
      v += __shfl_xor(v, 4); v += __shfl_xor(v, 8);
      lsum[m][r] = v;
    }
  if (col == 0){
    #pragma unroll
    for (int m = 0; m < 2; m++)
      #pragma unroll
      for (int r = 0; r < 4; r++)
        l_lds[w*BQ + m*16 + kg*4 + r] = lsum[m][r];
  }
  __syncthreads();
  if (tid < BQ){
    float t = 0.f;
    #pragma unroll
    for (int ww = 0; ww < 8; ww++) t += l_lds[ww*BQ + tid];
    l_inv[tid] = 1.f / t;
  }
  __syncthreads();

  {
    int ri    = w >> 2;
    int dbase = (w & 3) * 16;
    const float* vp = (ri ? v_imag : v_real) + bhSD;
    f32x4 acc[2]; acc[0] = (f32x4)(0.f); acc[1] = (f32x4)(0.f);
    for (int c = 0; c < 64; c++){
      int k0 = c*32 + kg*8;
      short8 bv;
      #pragma unroll
      for (int j = 0; j < 8; j++)
        bv[j] = (short)f2bf(vp[(size_t)(k0 + j) * D + dbase + col]);
      #pragma unroll
      for (int m = 0; m < 2; m++){
        short8 av = *(const short8*)(lds + eoff(m*16 + col, k0));
        acc[m] = __builtin_amdgcn_mfma_f32_16x16x32_bf16(av, bv, acc[m], 0, 0, 0);
      }
    }
    float* outp = out + (ri ? OUTSZ : 0) + bhSD;
    #pragma unroll
    for (int m = 0; m < 2; m++)
      #pragma unroll
      for (int r = 0; r < 4; r++){
        int row = m*16 + kg*4 + r;
        outp[(size_t)(qbase + row) * D + dbase + col] = acc[m][r] * l_inv[row];
      }
  }

  {
    float* attnp = out + 2*OUTSZ + (size_t)bh*S*S + (size_t)qbase*S;
    #pragma unroll
    for (int g = 0; g < 16; g++){
      int flat = g*4096 + tid*8;
      int row  = flat >> 11;
      int k    = flat & 2047;
      short8 ev = *(const short8*)(lds + eoff(row, k));
      float inv = l_inv[row];
      float4 o0, o1;
      o0.x = bf2f((unsigned short)ev[0]) * inv;
      o0.y = bf2f((unsigned short)ev[1]) * inv;
      o0.z = bf2f((unsigned short)ev[2]) * inv;
      o0.w = bf2f((unsigned short)ev[3]) * inv;
      o1.x = bf2f((unsigned short)ev[4]) * inv;
      o1.y = bf2f((unsigned short)ev[5]) * inv;
      o1.z = bf2f((unsigned short)ev[6]) * inv;
      o1.w = bf2f((unsigned short)ev[7]) * inv;
      *(float4*)(attnp + (size_t)row*S + k)     = o0;
      *(float4*)(attnp + (size_t)row*S + k + 4) = o1;
    }
  }
}

extern "C" void kernel_launch(void* const* d_in, const int* in_sizes, int n_in,
                              void* d_out, int out_size, void* d_ws, size_t ws_size,
                              hipStream_t stream)
{
  const float* qr = (const float*)d_in[0];
  const float* qi = (const float*)d_in[1];
  const float* kr = (const float*)d_in[2];
  const float* ki = (const float*)d_in[3];
  const float* vr = (const float*)d_in[4];
  const float* vi = (const float*)d_in[5];
  const int*   mk = (const int*)d_in[6];
  float* out = (float*)d_out;

  if (ws_size >= WS_FULL){
    unsigned short* kcat = (unsigned short*)((char*)d_ws + KCAT_OFF);
    unsigned short* vt   = (unsigned short*)((char*)d_ws + VT_OFF);
    unsigned char*  mt   = (unsigned char*)((char*)d_ws + MT_OFF);
    unsigned short* e_ws = (unsigned short*)((char*)d_ws + E_OFF);
    float*          linv = (float*)((char*)d_ws + LINV_OFF);
    conv_k<<<dim3(NBH*S*128/8/256), dim3(256), 0, stream>>>(kr, ki, kcat);
    conv_v<<<dim3(2*NBH*32),        dim3(256), 0, stream>>>(vr, vi, vt);
    conv_m<<<dim3(NB*32*32),        dim3(256), 0, stream>>>(mk, mt);
    score_kernel<<<dim3(NBLK), dim3(512), 0, stream>>>(qr, qi, kcat, mt, e_ws, linv);
    pv_kernel<<<dim3(NBLK),    dim3(512), 0, stream>>>(e_ws, vt, linv, out);
  } else if (ws_size >= WS_NEED){
    unsigned short* kcat = (unsigned short*)((char*)d_ws + KCAT_OFF);
    unsigned short* vt   = (unsigned short*)((char*)d_ws + VT_OFF);
    unsigned char*  mt   = (unsigned char*)((char*)d_ws + MT_OFF);
    conv_k<<<dim3(NBH*S*128/8/256), dim3(256), 0, stream>>>(kr, ki, kcat);
    conv_v<<<dim3(2*NBH*32),        dim3(256), 0, stream>>>(vr, vi, vt);
    conv_m<<<dim3(NB*32*32),        dim3(256), 0, stream>>>(mk, mt);
    size_t ldsb = (size_t)BQ*S*2 + (size_t)16*BQ*4 + (size_t)BQ*4;
    cattn_fused<<<dim3(NBLK), dim3(1024), ldsb, stream>>>(qr, qi, kcat, vt, mt, out);
  } else {
    size_t ldsb = (size_t)BQ*S*2 + (size_t)8*BQ*4 + (size_t)BQ*4;
    cattn_kernel<<<dim3(NBLK), dim3(512), ldsb, stream>>>(qr, qi, kr, ki, vr, vi, mk, out);
  }
}

// Round 7
// 399.613 us; speedup vs baseline: 1.4382x; 1.4382x over previous
//
#include <hip/hip_runtime.h>

#define S     2048
#define D     64
#define NH    12
#define NB    2
#define NBH   (NB*NH)       // 24
#define OUTSZ ((size_t)NBH*S*D)

#define BQ    32
#define QT    (S/BQ)        // 64
#define NBLK  (NBH*QT)      // 1536

// workspace layout (bytes)
#define KF_OFF    0
#define KF_SZ     ((size_t)NBH*S*128*2)        // 12582912 (fragment-ordered K)
#define VF_OFF    (KF_OFF + KF_SZ)
#define VF_SZ     ((size_t)2*NBH*D*S*2)        // 12582912 (fragment-ordered V)
#define MQ_OFF    (VF_OFF + VF_SZ)
#define MQ_SZ     ((size_t)NB*QT*S*4)          // 1048576 (32-row bitmasks)
#define MQ_SLOT   ((size_t)NB*S*S)             // keep old slot size for offsets
#define E_OFF     (MQ_OFF + MQ_SLOT)
#define E_SZ      ((size_t)NBH*S*S*2)          // 201326592
#define LINV_OFF  (E_OFF + E_SZ)
#define LINV_SZ   ((size_t)NBH*S*4)
#define WS_FULL   (LINV_OFF + LINV_SZ)         // 235077632

typedef __attribute__((ext_vector_type(8))) short short8;
typedef __attribute__((ext_vector_type(4))) float f32x4;

__device__ __forceinline__ unsigned short f2bf(float x){
  unsigned u = __builtin_bit_cast(unsigned, x);
  u += 0x7fffu + ((u >> 16) & 1u);       // RTNE
  return (unsigned short)(u >> 16);
}
__device__ __forceinline__ float bf2f(unsigned short h){
  unsigned u = ((unsigned)h) << 16;
  return __builtin_bit_cast(float, u);
}
__device__ __forceinline__ short8 pack8(const float4& a, const float4& b, float sc){
  short8 r;
  r[0]=(short)f2bf(a.x*sc); r[1]=(short)f2bf(a.y*sc);
  r[2]=(short)f2bf(a.z*sc); r[3]=(short)f2bf(a.w*sc);
  r[4]=(short)f2bf(b.x*sc); r[5]=(short)f2bf(b.y*sc);
  r[6]=(short)f2bf(b.z*sc); r[7]=(short)f2bf(b.w*sc);
  return r;
}
__device__ __forceinline__ int eoff(int row, int key){
  return ((row << 12) | (key << 1)) ^ ((row & 7) << 4);
}

// ------- conv_k: K -> fragment order kf[bh][grp64][eo2][kc4][lane64][8] -------
// value = concat(kr,ki)[bh][key = grp*32 + 2*(lane&15) + eo][d = kc*32 + (lane>>4)*8 + j]
__global__ __launch_bounds__(256) void conv_k(const float* __restrict__ kr,
                                              const float* __restrict__ ki,
                                              unsigned short* __restrict__ kf){
  int idx  = blockIdx.x*256 + threadIdx.x;     // 786432 total
  int lane = idx & 63;
  int kc   = (idx >> 6) & 3;
  int eo   = (idx >> 8) & 1;
  int grp  = (idx >> 9) & 63;
  int bh   = idx >> 15;
  int key  = grp*32 + 2*(lane & 15) + eo;
  int d0   = kc*32 + (lane >> 4)*8;
  const float* src = (d0 < 64) ? kr + ((size_t)bh*S + key)*64 + d0
                               : ki + ((size_t)bh*S + key)*64 + (d0 - 64);
  float4 a = *(const float4*)(src);
  float4 b = *(const float4*)(src + 4);
  *(short8*)(kf + (size_t)idx*8) = pack8(a, b, 1.f);
}

// ------- conv_v: V -> fragment order vf[ri*NBH+bh][dg4][c64][lane64][8] -------
// value = V[s = c*32 + (lane>>4)*8 + j][d = dg*16 + (lane&15)]
__global__ __launch_bounds__(256) void conv_v(const float* __restrict__ vr,
                                              const float* __restrict__ vi,
                                              unsigned short* __restrict__ vf){
  __shared__ unsigned short tile[64][65];      // [d][s_local]
  int bid = blockIdx.x;
  int ri  = bid / (NBH*32);
  int rem = bid % (NBH*32);
  int bh  = rem / 32;
  int s0  = (rem % 32) * 64;
  const float* vp = (ri ? vi : vr) + (size_t)bh*S*D;
  int t = threadIdx.x;
  #pragma unroll
  for (int it = 0; it < 4; it++){
    int row = (t >> 4) + it*16;                // s_local
    int c4  = (t & 15) * 4;                    // d
    float4 v = *(const float4*)(vp + (size_t)(s0+row)*D + c4);
    tile[c4+0][row] = f2bf(v.x);
    tile[c4+1][row] = f2bf(v.y);
    tile[c4+2][row] = f2bf(v.z);
    tile[c4+3][row] = f2bf(v.w);
  }
  __syncthreads();
  unsigned short* dst = vf + (size_t)(ri*NBH + bh) * 4*64*64*8;
  #pragma unroll
  for (int u = 0; u < 2; u++){
    int comb = u*256 + t;                      // 512 combos = dg*2cp*64lane
    int lane = comb & 63;
    int cp   = (comb >> 6) & 1;
    int dg   = comb >> 7;
    int c    = s0/32 + cp;
    int d    = dg*16 + (lane & 15);
    int sl   = cp*32 + (lane >> 4)*8;          // s_local
    short8 o;
    #pragma unroll
    for (int j = 0; j < 8; j++) o[j] = (short)tile[d][sl + j];
    *(short8*)(dst + (((size_t)dg*64 + c)*64 + lane)*8) = o;
  }
}

// ------- conv_m: mask -> mq32[b][qt][key] bitmask of 32 q-rows -------
__global__ __launch_bounds__(256) void conv_m(const int* __restrict__ mask,
                                              unsigned* __restrict__ mq){
  int b  = blockIdx.x >> 6;
  int qt = blockIdx.x & 63;
  int qbase = qt * BQ;
  int t = threadIdx.x;
  #pragma unroll
  for (int it = 0; it < 8; it++){
    int key = it*256 + t;
    unsigned bits = 0;
    #pragma unroll
    for (int j = 0; j < 32; j++)
      bits |= (mask[((size_t)b*S + qbase + j)*S + key] ? 1u : 0u) << j;
    mq[((size_t)b*64 + qt)*S + key] = bits;
  }
}

// ------- kernel A: scores -> e(bf16 row-major) + l_inv; fragment-ordered loads ----
__global__ __launch_bounds__(512) void score_kernel(
    const float* __restrict__ q_real, const float* __restrict__ q_imag,
    const unsigned short* __restrict__ kf,
    const unsigned* __restrict__ mq,
    unsigned short* __restrict__ e_ws, float* __restrict__ linv_ws)
{
  __shared__ float l_red[8*BQ];

  int bid = blockIdx.x;
  int swz = (bid & 7) * (NBLK/8) + (bid >> 3);
  int bh    = swz / QT;
  int qt    = swz % QT;
  int b0    = bh / NH;
  int qbase = qt * BQ;

  int tid  = threadIdx.x;
  int w    = tid >> 6;       // 0..7
  int lane = tid & 63;
  int col  = lane & 15;
  int kg   = lane >> 4;

  const size_t bhSD = (size_t)bh * S * D;

  // Q fragments: A_r = [qr,qi]/8, A_i = [qi,-qr]/8 (K=128 over 4 chunks of 32)
  short8 a_r[2][4], a_i[2][4];
  #pragma unroll
  for (int m = 0; m < 2; m++){
    const float* qrp = q_real + bhSD + (size_t)(qbase + m*16 + col) * D;
    const float* qip = q_imag + bhSD + (size_t)(qbase + m*16 + col) * D;
    #pragma unroll
    for (int h = 0; h < 2; h++){
      int d0 = h*32 + kg*8;
      float4 r0 = *(const float4*)(qrp + d0);
      float4 r1 = *(const float4*)(qrp + d0 + 4);
      float4 i0 = *(const float4*)(qip + d0);
      float4 i1 = *(const float4*)(qip + d0 + 4);
      a_r[m][h]   = pack8(r0, r1,  0.125f);
      a_r[m][2+h] = pack8(i0, i1,  0.125f);
      a_i[m][h]   = a_r[m][2+h];
      a_i[m][2+h] = pack8(r0, r1, -0.125f);
    }
  }

  float lsum[2][4] = {{0.f,0.f,0.f,0.f},{0.f,0.f,0.f,0.f}};
  unsigned short* estripe = e_ws + ((size_t)bh*S + qbase) * S;
  const unsigned* mqp = mq + ((size_t)b0*64 + qt) * S;

  for (int t = 0; t < 8; t++){
    int grp = w*8 + t;                           // 32-key group
    const unsigned short* kb = kf + (size_t)(bh*64 + grp) * 2*4*64*8;
    short8 bvA[4], bvB[4];
    #pragma unroll
    for (int kc = 0; kc < 4; kc++){
      bvA[kc] = *(const short8*)(kb + ((size_t)kc*64 + lane)*8);           // eo=0
      bvB[kc] = *(const short8*)(kb + ((size_t)(4+kc)*64 + lane)*8);       // eo=1
    }
    int keyA = grp*32 + 2*col;
    unsigned umA = mqp[keyA];
    unsigned umB = mqp[keyA + 1];

    f32x4 aAr[2], aAi[2], aBr[2], aBi[2];
    #pragma unroll
    for (int m = 0; m < 2; m++){
      aAr[m] = (f32x4)(0.f); aAi[m] = (f32x4)(0.f);
      aBr[m] = (f32x4)(0.f); aBi[m] = (f32x4)(0.f);
    }
    #pragma unroll
    for (int m = 0; m < 2; m++)
      #pragma unroll
      for (int kc = 0; kc < 4; kc++){
        aAr[m] = __builtin_amdgcn_mfma_f32_16x16x32_bf16(a_r[m][kc], bvA[kc], aAr[m], 0, 0, 0);
        aAi[m] = __builtin_amdgcn_mfma_f32_16x16x32_bf16(a_i[m][kc], bvA[kc], aAi[m], 0, 0, 0);
        aBr[m] = __builtin_amdgcn_mfma_f32_16x16x32_bf16(a_r[m][kc], bvB[kc], aBr[m], 0, 0, 0);
        aBi[m] = __builtin_amdgcn_mfma_f32_16x16x32_bf16(a_i[m][kc], bvB[kc], aBi[m], 0, 0, 0);
      }
    #pragma unroll
    for (int m = 0; m < 2; m++){
      #pragma unroll
      for (int r = 0; r < 4; r++){
        int row = m*16 + kg*4 + r;
        float arA = aAr[m][r], aiA = aAi[m][r];
        float sA  = sqrtf(arA*arA + aiA*aiA);
        float eA  = ((umA >> row) & 1u) ? __expf(sA) : 0.f;
        float arB = aBr[m][r], aiB = aBi[m][r];
        float sB  = sqrtf(arB*arB + aiB*aiB);
        float eB  = ((umB >> row) & 1u) ? __expf(sB) : 0.f;
        lsum[m][r] += eA + eB;
        unsigned pk = (unsigned)f2bf(eA) | ((unsigned)f2bf(eB) << 16);
        *(unsigned*)(estripe + (size_t)row*S + keyA) = pk;
      }
    }
  }

  #pragma unroll
  for (int m = 0; m < 2; m++)
    #pragma unroll
    for (int r = 0; r < 4; r++){
      float v = lsum[m][r];
      v += __shfl_xor(v, 1); v += __shfl_xor(v, 2);
      v += __shfl_xor(v, 4); v += __shfl_xor(v, 8);
      lsum[m][r] = v;
    }
  if (col == 0){
    #pragma unroll
    for (int m = 0; m < 2; m++)
      #pragma unroll
      for (int r = 0; r < 4; r++)
        l_red[w*BQ + m*16 + kg*4 + r] = lsum[m][r];
  }
  __syncthreads();
  if (tid < BQ){
    float t = 0.f;
    #pragma unroll
    for (int ww = 0; ww < 8; ww++) t += l_red[ww*BQ + tid];
    linv_ws[(size_t)bh*S + qbase + tid] = 1.f / t;
  }
}

// ------- kernel B: PV via LDS-staged e + fragment-ordered V; attn linear phase ----
#define EB_STRIDE 272            // 256B row + 16B pad
#define EB_SZ     (32*EB_STRIDE) // 8704 per buffer

__global__ __launch_bounds__(512) void pv_kernel(
    const unsigned short* __restrict__ e_ws,
    const unsigned short* __restrict__ vf,
    const float* __restrict__ linv_ws,
    float* __restrict__ out)
{
  __shared__ __align__(16) char ebuf[2*EB_SZ];

  int bid = blockIdx.x;
  int swz = (bid & 7) * (NBLK/8) + (bid >> 3);
  int bh    = swz / QT;
  int qt    = swz % QT;
  int qbase = qt * BQ;

  int tid  = threadIdx.x;
  int w    = tid >> 6;       // 0..7
  int lane = tid & 63;
  int col  = lane & 15;
  int kg   = lane >> 4;

  const size_t bhSD = (size_t)bh * S * D;
  const float* linv = linv_ws + (size_t)bh*S + qbase;
  const unsigned short* estripe = e_ws + ((size_t)bh*S + qbase) * S;

  int ri = w >> 2;
  int dg = w & 3;
  const unsigned short* vbase = vf + ((size_t)(ri*NBH + bh)*4 + dg) * 64*64*8;

  // staging addresses: thread t covers row t>>4, 16B chunk (t&15)
  int srow = tid >> 4;
  int sc8  = (tid & 15) * 8;                       // elem offset within chunk row
  const unsigned short* esrc = estripe + (size_t)srow*S + sc8;
  char* edst = ebuf + srow*EB_STRIDE + (tid & 15)*16;

  // prologue: stage chunk 0 into buf0, preload chunk 1
  short8 sreg = *(const short8*)(esrc);
  *(short8*)(edst) = sreg;
  sreg = *(const short8*)(esrc + 128);
  __syncthreads();

  f32x4 acc0 = (f32x4)(0.f), acc1 = (f32x4)(0.f);

  for (int ck = 0; ck < 16; ck++){
    int cur = ck & 1;
    if (ck < 15) *(short8*)(edst + (cur^1)*EB_SZ) = sreg;   // write chunk ck+1
    if (ck < 14) sreg = *(const short8*)(esrc + (size_t)(ck+2)*128);

    const char* eb = ebuf + cur*EB_SZ;
    short8 bvv[4];
    #pragma unroll
    for (int cl = 0; cl < 4; cl++)
      bvv[cl] = *(const short8*)(vbase + ((size_t)(ck*4 + cl)*64 + lane)*8);
    #pragma unroll
    for (int cl = 0; cl < 4; cl++){
      short8 a0 = *(const short8*)(eb + col*EB_STRIDE + cl*64 + kg*16);
      short8 a1 = *(const short8*)(eb + (16+col)*EB_STRIDE + cl*64 + kg*16);
      acc0 = __builtin_amdgcn_mfma_f32_16x16x32_bf16(a0, bvv[cl], acc0, 0, 0, 0);
      acc1 = __builtin_amdgcn_mfma_f32_16x16x32_bf16(a1, bvv[cl], acc1, 0, 0, 0);
    }
    __syncthreads();
  }

  float* outp = out + (ri ? OUTSZ : 0) + bhSD;
  #pragma unroll
  for (int r = 0; r < 4; r++){
    int row0 = kg*4 + r;
    outp[(size_t)(qbase + row0) * D + dg*16 + col]      = acc0[r] * linv[row0];
    outp[(size_t)(qbase + 16 + row0) * D + dg*16 + col] = acc1[r] * linv[16 + row0];
  }

  // attn = e * l_inv : fully linear reads and stores (proven r5 pattern)
  {
    float* attnp = out + 2*OUTSZ + (size_t)bh*S*S + (size_t)qbase*S;
    #pragma unroll
    for (int g = 0; g < 16; g++){
      int flat = g*4096 + tid*8;
      int row  = flat >> 11;
      int k    = flat & 2047;
      short8 ev = *(const short8*)(estripe + (size_t)row*S + k);
      float inv = linv[row];
      float4 o0, o1;
      o0.x = bf2f((unsigned short)ev[0]) * inv;
      o0.y = bf2f((unsigned short)ev[1]) * inv;
      o0.z = bf2f((unsigned short)ev[2]) * inv;
      o0.w = bf2f((unsigned short)ev[3]) * inv;
      o1.x = bf2f((unsigned short)ev[4]) * inv;
      o1.y = bf2f((unsigned short)ev[5]) * inv;
      o1.z = bf2f((unsigned short)ev[6]) * inv;
      o1.w = bf2f((unsigned short)ev[7]) * inv;
      *(float4*)(attnp + (size_t)row*S + k)     = o0;
      *(float4*)(attnp + (size_t)row*S + k + 4) = o1;
    }
  }
}

// ---------------- tier-3: no-workspace fallback (round-2 kernel, proven) ----------
__global__ __launch_bounds__(512) void cattn_kernel(
    const float* __restrict__ q_real, const float* __restrict__ q_imag,
    const float* __restrict__ k_real, const float* __restrict__ k_imag,
    const float* __restrict__ v_real, const float* __restrict__ v_imag,
    const int*   __restrict__ mask,   float* __restrict__ out)
{
  extern __shared__ __align__(16) char lds[];
  float* l_lds = (float*)(lds + (size_t)BQ*S*2);
  float* l_inv = l_lds + 8*BQ;

  int bid = blockIdx.x;
  int swz = (bid & 7) * (NBLK/8) + (bid >> 3);
  int bh    = swz / QT;
  int qt    = swz % QT;
  int b0    = bh / NH;
  int qbase = qt * BQ;

  int tid  = threadIdx.x;
  int w    = tid >> 6;
  int lane = tid & 63;
  int col  = lane & 15;
  int kg   = lane >> 4;

  const size_t bhSD = (size_t)bh * S * D;

  short8 a_r[2][4], a_i[2][4];
  #pragma unroll
  for (int m = 0; m < 2; m++){
    const float* qrp = q_real + bhSD + (size_t)(qbase + m*16 + col) * D;
    const float* qip = q_imag + bhSD + (size_t)(qbase + m*16 + col) * D;
    #pragma unroll
    for (int h = 0; h < 2; h++){
      int d0 = h*32 + kg*8;
      float4 r0 = *(const float4*)(qrp + d0);
      float4 r1 = *(const float4*)(qrp + d0 + 4);
      float4 i0 = *(const float4*)(qip + d0);
      float4 i1 = *(const float4*)(qip + d0 + 4);
      a_r[m][h]   = pack8(r0, r1,  0.125f);
      a_r[m][2+h] = pack8(i0, i1,  0.125f);
      a_i[m][h]   = a_r[m][2+h];
      a_i[m][2+h] = pack8(r0, r1, -0.125f);
    }
  }

  float lsum[2][4] = {{0.f,0.f,0.f,0.f},{0.f,0.f,0.f,0.f}};
  const int* mrow = mask + (size_t)b0 * S * S;

  for (int t = 0; t < 16; t++){
    int key = w*256 + t*16 + col;
    const float* krp = k_real + bhSD + (size_t)key * D;
    const float* kip = k_imag + bhSD + (size_t)key * D;
    short8 bv[4];
    #pragma unroll
    for (int h = 0; h < 2; h++){
      int d0 = h*32 + kg*8;
      float4 r0 = *(const float4*)(krp + d0);
      float4 r1 = *(const float4*)(krp + d0 + 4);
      float4 i0 = *(const float4*)(kip + d0);
      float4 i1 = *(const float4*)(kip + d0 + 4);
      bv[h]   = pack8(r0, r1, 1.f);
      bv[2+h] = pack8(i0, i1, 1.f);
    }
    f32x4 accr[2], acci[2];
    #pragma unroll
    for (int m = 0; m < 2; m++){ accr[m] = (f32x4)(0.f); acci[m] = (f32x4)(0.f); }
    #pragma unroll
    for (int m = 0; m < 2; m++)
      #pragma unroll
      for (int kc = 0; kc < 4; kc++){
        accr[m] = __builtin_amdgcn_mfma_f32_16x16x32_bf16(a_r[m][kc], bv[kc], accr[m], 0, 0, 0);
        acci[m] = __builtin_amdgcn_mfma_f32_16x16x32_bf16(a_i[m][kc], bv[kc], acci[m], 0, 0, 0);
      }
    #pragma unroll
    for (int m = 0; m < 2; m++){
      int qrow_g = qbase + m*16 + kg*4;
      #pragma unroll
      for (int r = 0; r < 4; r++){
        float ar = accr[m][r], ai = acci[m][r];
        float s  = sqrtf(ar*ar + ai*ai);
        int  mv  = mrow[(size_t)(qrow_g + r) * S + key];
        float ex = __expf(s);
        float e  = mv ? ex : 0.f;
        lsum[m][r] += e;
        *(unsigned short*)(lds + eoff(m*16 + kg*4 + r, key)) = f2bf(e);
      }
    }
  }

  #pragma unroll
  for (int m = 0; m < 2; m++)
    #pragma unroll
    for (int r = 0; r < 4; r++){
      float v = lsum[m][r];
      v += __shfl_xor(v, 1); v += __shfl_xor(v, 2);
      v += __shfl_xor(v, 4); v += __shfl_xor(v, 8);
      lsum[m][r] = v;
    }
  if (col == 0){
    #pragma unroll
    for (int m = 0; m < 2; m++)
      #pragma unroll
      for (int r = 0; r < 4; r++)
        l_lds[w*BQ + m*16 + kg*4 + r] = lsum[m][r];
  }
  __syncthreads();
  if (tid < BQ){
    float t = 0.f;
    #pragma unroll
    for (int ww = 0; ww < 8; ww++) t += l_lds[ww*BQ + tid];
    l_inv[tid] = 1.f / t;
  }
  __syncthreads();

  {
    int ri    = w >> 2;
    int dbase = (w & 3) * 16;
    const float* vp = (ri ? v_imag : v_real) + bhSD;
    f32x4 acc[2]; acc[0] = (f32x4)(0.f); acc[1] = (f32x4)(0.f);
    for (int c = 0; c < 64; c++){
      int k0 = c*32 + kg*8;
      short8 bv;
      #pragma unroll
      for (int j = 0; j < 8; j++)
        bv[j] = (short)f2bf(vp[(size_t)(k0 + j) * D + dbase + col]);
      #pragma unroll
      for (int m = 0; m < 2; m++){
        short8 av = *(const short8*)(lds + eoff(m*16 + col, k0));
        acc[m] = __builtin_amdgcn_mfma_f32_16x16x32_bf16(av, bv, acc[m], 0, 0, 0);
      }
    }
    float* outp = out + (ri ? OUTSZ : 0) + bhSD;
    #pragma unroll
    for (int m = 0; m < 2; m++)
      #pragma unroll
      for (int r = 0; r < 4; r++){
        int row = m*16 + kg*4 + r;
        outp[(size_t)(qbase + row) * D + dbase + col] = acc[m][r] * l_inv[row];
      }
  }

  {
    float* attnp = out + 2*OUTSZ + (size_t)bh*S*S + (size_t)qbase*S;
    #pragma unroll
    for (int g = 0; g < 16; g++){
      int flat = g*4096 + tid*8;
      int row  = flat >> 11;
      int k    = flat & 2047;
      short8 ev = *(const short8*)(lds + eoff(row, k));
      float inv = l_inv[row];
      float4 o0, o1;
      o0.x = bf2f((unsigned short)ev[0]) * inv;
      o0.y = bf2f((unsigned short)ev[1]) * inv;
      o0.z = bf2f((unsigned short)ev[2]) * inv;
      o0.w = bf2f((unsigned short)ev[3]) * inv;
      o1.x = bf2f((unsigned short)ev[4]) * inv;
      o1.y = bf2f((unsigned short)ev[5]) * inv;
      o1.z = bf2f((unsigned short)ev[6]) * inv;
      o1.w = bf2f((unsigned short)ev[7]) * inv;
      *(float4*)(attnp + (size_t)row*S + k)     = o0;
      *(float4*)(attnp + (size_t)row*S + k + 4) = o1;
    }
  }
}

extern "C" void kernel_launch(void* const* d_in, const int* in_sizes, int n_in,
                              void* d_out, int out_size, void* d_ws, size_t ws_size,
                              hipStream_t stream)
{
  const float* qr = (const float*)d_in[0];
  const float* qi = (const float*)d_in[1];
  const float* kr = (const float*)d_in[2];
  const float* ki = (const float*)d_in[3];
  const float* vr = (const float*)d_in[4];
  const float* vi = (const float*)d_in[5];
  const int*   mk = (const int*)d_in[6];
  float* out = (float*)d_out;

  if (ws_size >= WS_FULL){
    unsigned short* kf   = (unsigned short*)((char*)d_ws + KF_OFF);
    unsigned short* vf   = (unsigned short*)((char*)d_ws + VF_OFF);
    unsigned*       mq   = (unsigned*)((char*)d_ws + MQ_OFF);
    unsigned short* e_ws = (unsigned short*)((char*)d_ws + E_OFF);
    float*          linv = (float*)((char*)d_ws + LINV_OFF);
    conv_k<<<dim3(3072),     dim3(256), 0, stream>>>(kr, ki, kf);
    conv_v<<<dim3(2*NBH*32), dim3(256), 0, stream>>>(vr, vi, vf);
    conv_m<<<dim3(NB*QT),    dim3(256), 0, stream>>>(mk, mq);
    score_kernel<<<dim3(NBLK), dim3(512), 0, stream>>>(qr, qi, kf, mq, e_ws, linv);
    pv_kernel<<<dim3(NBLK),    dim3(512), 0, stream>>>(e_ws, vf, linv, out);
  } else {
    size_t ldsb = (size_t)BQ*S*2 + (size_t)8*BQ*4 + (size_t)BQ*4;
    cattn_kernel<<<dim3(NBLK), dim3(512), ldsb, stream>>>(qr, qi, kr, ki, vr, vi, mk, out);
  }
}

// Round 8
// 372.173 us; speedup vs baseline: 1.5442x; 1.0737x over previous
//
#include <hip/hip_runtime.h>

#define S     2048
#define D     64
#define NH    12
#define NB    2
#define NBH   (NB*NH)       // 24
#define OUTSZ ((size_t)NBH*S*D)

#define BQ    32
#define QT    (S/BQ)        // 64
#define NBLK  (NBH*QT)      // 1536

// workspace layout (bytes)
#define KF_OFF    0
#define KF_SZ     ((size_t)NBH*S*128*2)        // 12582912 (fragment-ordered K)
#define VF_OFF    (KF_OFF + KF_SZ)
#define VF_SZ     ((size_t)2*NBH*D*S*2)        // 12582912 (fragment-ordered V)
#define MQ_OFF    (VF_OFF + VF_SZ)
#define MQ_SZ     ((size_t)NB*QT*S*4)          // 1048576 (32-row bitmasks)
#define MQ_SLOT   ((size_t)NB*S*S)             // keep old slot size for offsets
#define E_OFF     (MQ_OFF + MQ_SLOT)
#define E_SZ      ((size_t)NBH*S*S*2)          // 201326592
#define LINV_OFF  (E_OFF + E_SZ)
#define LINV_SZ   ((size_t)NBH*S*4)
#define WS_FULL   (LINV_OFF + LINV_SZ)         // 235077632

typedef __attribute__((ext_vector_type(8))) short short8;
typedef __attribute__((ext_vector_type(4))) float f32x4;

__device__ __forceinline__ unsigned short f2bf(float x){
  unsigned u = __builtin_bit_cast(unsigned, x);
  u += 0x7fffu + ((u >> 16) & 1u);       // RTNE
  return (unsigned short)(u >> 16);
}
__device__ __forceinline__ float bf2f(unsigned short h){
  unsigned u = ((unsigned)h) << 16;
  return __builtin_bit_cast(float, u);
}
__device__ __forceinline__ short8 pack8(const float4& a, const float4& b, float sc){
  short8 r;
  r[0]=(short)f2bf(a.x*sc); r[1]=(short)f2bf(a.y*sc);
  r[2]=(short)f2bf(a.z*sc); r[3]=(short)f2bf(a.w*sc);
  r[4]=(short)f2bf(b.x*sc); r[5]=(short)f2bf(b.y*sc);
  r[6]=(short)f2bf(b.z*sc); r[7]=(short)f2bf(b.w*sc);
  return r;
}
__device__ __forceinline__ int eoff(int row, int key){
  return ((row << 12) | (key << 1)) ^ ((row & 7) << 4);
}
__device__ __forceinline__ void wr_attn8(float* dst, short8 v, float sc){
  float4 o0, o1;
  o0.x = bf2f((unsigned short)v[0]) * sc;
  o0.y = bf2f((unsigned short)v[1]) * sc;
  o0.z = bf2f((unsigned short)v[2]) * sc;
  o0.w = bf2f((unsigned short)v[3]) * sc;
  o1.x = bf2f((unsigned short)v[4]) * sc;
  o1.y = bf2f((unsigned short)v[5]) * sc;
  o1.z = bf2f((unsigned short)v[6]) * sc;
  o1.w = bf2f((unsigned short)v[7]) * sc;
  *(float4*)(dst)     = o0;
  *(float4*)(dst + 4) = o1;
}

// ------- conv_k: K -> fragment order kf[bh][grp64][eo2][kc4][lane64][8] -------
__global__ __launch_bounds__(256) void conv_k(const float* __restrict__ kr,
                                              const float* __restrict__ ki,
                                              unsigned short* __restrict__ kf){
  int idx  = blockIdx.x*256 + threadIdx.x;     // 786432 total
  int lane = idx & 63;
  int kc   = (idx >> 6) & 3;
  int eo   = (idx >> 8) & 1;
  int grp  = (idx >> 9) & 63;
  int bh   = idx >> 15;
  int key  = grp*32 + 2*(lane & 15) + eo;
  int d0   = kc*32 + (lane >> 4)*8;
  const float* src = (d0 < 64) ? kr + ((size_t)bh*S + key)*64 + d0
                               : ki + ((size_t)bh*S + key)*64 + (d0 - 64);
  float4 a = *(const float4*)(src);
  float4 b = *(const float4*)(src + 4);
  *(short8*)(kf + (size_t)idx*8) = pack8(a, b, 1.f);
}

// ------- conv_v: V -> fragment order vf[ri*NBH+bh][dg4][c64][lane64][8] -------
__global__ __launch_bounds__(256) void conv_v(const float* __restrict__ vr,
                                              const float* __restrict__ vi,
                                              unsigned short* __restrict__ vf){
  __shared__ unsigned short tile[64][65];      // [d][s_local]
  int bid = blockIdx.x;
  int ri  = bid / (NBH*32);
  int rem = bid % (NBH*32);
  int bh  = rem / 32;
  int s0  = (rem % 32) * 64;
  const float* vp = (ri ? vi : vr) + (size_t)bh*S*D;
  int t = threadIdx.x;
  #pragma unroll
  for (int it = 0; it < 4; it++){
    int row = (t >> 4) + it*16;                // s_local
    int c4  = (t & 15) * 4;                    // d
    float4 v = *(const float4*)(vp + (size_t)(s0+row)*D + c4);
    tile[c4+0][row] = f2bf(v.x);
    tile[c4+1][row] = f2bf(v.y);
    tile[c4+2][row] = f2bf(v.z);
    tile[c4+3][row] = f2bf(v.w);
  }
  __syncthreads();
  unsigned short* dst = vf + (size_t)(ri*NBH + bh) * 4*64*64*8;
  #pragma unroll
  for (int u = 0; u < 2; u++){
    int comb = u*256 + t;                      // 512 combos = dg*2cp*64lane
    int lane = comb & 63;
    int cp   = (comb >> 6) & 1;
    int dg   = comb >> 7;
    int c    = s0/32 + cp;
    int d    = dg*16 + (lane & 15);
    int sl   = cp*32 + (lane >> 4)*8;          // s_local
    short8 o;
    #pragma unroll
    for (int j = 0; j < 8; j++) o[j] = (short)tile[d][sl + j];
    *(short8*)(dst + (((size_t)dg*64 + c)*64 + lane)*8) = o;
  }
}

// ------- conv_m: mask -> mq32[b][qt][key] bitmask of 32 q-rows -------
__global__ __launch_bounds__(256) void conv_m(const int* __restrict__ mask,
                                              unsigned* __restrict__ mq){
  int b  = blockIdx.x >> 6;
  int qt = blockIdx.x & 63;
  int qbase = qt * BQ;
  int t = threadIdx.x;
  #pragma unroll
  for (int it = 0; it < 8; it++){
    int key = it*256 + t;
    unsigned bits = 0;
    #pragma unroll
    for (int j = 0; j < 32; j++)
      bits |= (mask[((size_t)b*S + qbase + j)*S + key] ? 1u : 0u) << j;
    mq[((size_t)b*64 + qt)*S + key] = bits;
  }
}

// ------- kernel A: scores -> e(bf16 row-major) + l_inv; fragment-ordered loads ----
__global__ __launch_bounds__(512) void score_kernel(
    const float* __restrict__ q_real, const float* __restrict__ q_imag,
    const unsigned short* __restrict__ kf,
    const unsigned* __restrict__ mq,
    unsigned short* __restrict__ e_ws, float* __restrict__ linv_ws)
{
  __shared__ float l_red[8*BQ];

  int bid = blockIdx.x;
  int swz = (bid & 7) * (NBLK/8) + (bid >> 3);
  int bh    = swz / QT;
  int qt    = swz % QT;
  int b0    = bh / NH;
  int qbase = qt * BQ;

  int tid  = threadIdx.x;
  int w    = tid >> 6;       // 0..7
  int lane = tid & 63;
  int col  = lane & 15;
  int kg   = lane >> 4;

  const size_t bhSD = (size_t)bh * S * D;

  // Q fragments: A_r = [qr,qi]/8, A_i = [qi,-qr]/8 (K=128 over 4 chunks of 32)
  short8 a_r[2][4], a_i[2][4];
  #pragma unroll
  for (int m = 0; m < 2; m++){
    const float* qrp = q_real + bhSD + (size_t)(qbase + m*16 + col) * D;
    const float* qip = q_imag + bhSD + (size_t)(qbase + m*16 + col) * D;
    #pragma unroll
    for (int h = 0; h < 2; h++){
      int d0 = h*32 + kg*8;
      float4 r0 = *(const float4*)(qrp + d0);
      float4 r1 = *(const float4*)(qrp + d0 + 4);
      float4 i0 = *(const float4*)(qip + d0);
      float4 i1 = *(const float4*)(qip + d0 + 4);
      a_r[m][h]   = pack8(r0, r1,  0.125f);
      a_r[m][2+h] = pack8(i0, i1,  0.125f);
      a_i[m][h]   = a_r[m][2+h];
      a_i[m][2+h] = pack8(r0, r1, -0.125f);
    }
  }

  float lsum[2][4] = {{0.f,0.f,0.f,0.f},{0.f,0.f,0.f,0.f}};
  unsigned short* estripe = e_ws + ((size_t)bh*S + qbase) * S;
  const unsigned* mqp = mq + ((size_t)b0*64 + qt) * S;

  for (int t = 0; t < 8; t++){
    int grp = w*8 + t;                           // 32-key group
    const unsigned short* kb = kf + (size_t)(bh*64 + grp) * 2*4*64*8;
    short8 bvA[4], bvB[4];
    #pragma unroll
    for (int kc = 0; kc < 4; kc++){
      bvA[kc] = *(const short8*)(kb + ((size_t)kc*64 + lane)*8);           // eo=0
      bvB[kc] = *(const short8*)(kb + ((size_t)(4+kc)*64 + lane)*8);       // eo=1
    }
    int keyA = grp*32 + 2*col;
    unsigned umA = mqp[keyA];
    unsigned umB = mqp[keyA + 1];

    f32x4 aAr[2], aAi[2], aBr[2], aBi[2];
    #pragma unroll
    for (int m = 0; m < 2; m++){
      aAr[m] = (f32x4)(0.f); aAi[m] = (f32x4)(0.f);
      aBr[m] = (f32x4)(0.f); aBi[m] = (f32x4)(0.f);
    }
    #pragma unroll
    for (int m = 0; m < 2; m++)
      #pragma unroll
      for (int kc = 0; kc < 4; kc++){
        aAr[m] = __builtin_amdgcn_mfma_f32_16x16x32_bf16(a_r[m][kc], bvA[kc], aAr[m], 0, 0, 0);
        aAi[m] = __builtin_amdgcn_mfma_f32_16x16x32_bf16(a_i[m][kc], bvA[kc], aAi[m], 0, 0, 0);
        aBr[m] = __builtin_amdgcn_mfma_f32_16x16x32_bf16(a_r[m][kc], bvB[kc], aBr[m], 0, 0, 0);
        aBi[m] = __builtin_amdgcn_mfma_f32_16x16x32_bf16(a_i[m][kc], bvB[kc], aBi[m], 0, 0, 0);
      }
    #pragma unroll
    for (int m = 0; m < 2; m++){
      #pragma unroll
      for (int r = 0; r < 4; r++){
        int row = m*16 + kg*4 + r;
        float arA = aAr[m][r], aiA = aAi[m][r];
        float sA  = sqrtf(arA*arA + aiA*aiA);
        float eA  = ((umA >> row) & 1u) ? __expf(sA) : 0.f;
        float arB = aBr[m][r], aiB = aBi[m][r];
        float sB  = sqrtf(arB*arB + aiB*aiB);
        float eB  = ((umB >> row) & 1u) ? __expf(sB) : 0.f;
        lsum[m][r] += eA + eB;
        unsigned pk = (unsigned)f2bf(eA) | ((unsigned)f2bf(eB) << 16);
        *(unsigned*)(estripe + (size_t)row*S + keyA) = pk;
      }
    }
  }

  #pragma unroll
  for (int m = 0; m < 2; m++)
    #pragma unroll
    for (int r = 0; r < 4; r++){
      float v = lsum[m][r];
      v += __shfl_xor(v, 1); v += __shfl_xor(v, 2);
      v += __shfl_xor(v, 4); v += __shfl_xor(v, 8);
      lsum[m][r] = v;
    }
  if (col == 0){
    #pragma unroll
    for (int m = 0; m < 2; m++)
      #pragma unroll
      for (int r = 0; r < 4; r++)
        l_red[w*BQ + m*16 + kg*4 + r] = lsum[m][r];
  }
  __syncthreads();
  if (tid < BQ){
    float t = 0.f;
    #pragma unroll
    for (int ww = 0; ww < 8; ww++) t += l_red[ww*BQ + tid];
    linv_ws[(size_t)bh*S + qbase + tid] = 1.f / t;
  }
}

// ------- kernel B: PV via LDS-staged e; attn written at stage time from regs ----
// 256-key superchunks: 8 iterations, 8 barriers. Row stride 528 B = even bank
// pattern (start bank 4*(col+kg)+16cl mod 32, 8 groups x 8 lanes -> min-cycles).
#define EB_STRIDE 528
#define EB_SZ     (32*EB_STRIDE)   // 16896 per buffer, 33792 total

__global__ __launch_bounds__(512) void pv_kernel(
    const unsigned short* __restrict__ e_ws,
    const unsigned short* __restrict__ vf,
    const float* __restrict__ linv_ws,
    float* __restrict__ out)
{
  __shared__ __align__(16) char ebuf[2*EB_SZ];

  int bid = blockIdx.x;
  int swz = (bid & 7) * (NBLK/8) + (bid >> 3);
  int bh    = swz / QT;
  int qt    = swz % QT;
  int qbase = qt * BQ;

  int tid  = threadIdx.x;
  int w    = tid >> 6;       // 0..7
  int lane = tid & 63;
  int col  = lane & 15;
  int kg   = lane >> 4;

  const size_t bhSD = (size_t)bh * S * D;
  const float* linv = linv_ws + (size_t)bh*S + qbase;
  const unsigned short* estripe = e_ws + ((size_t)bh*S + qbase) * S;

  int ri = w >> 2;
  int dg = w & 3;
  const unsigned short* vbase = vf + ((size_t)(ri*NBH + bh)*4 + dg) * 64*64*8;

  // staging: thread covers row tid>>4, 16B slot tid&15; superchunk = 256 keys
  int srow = tid >> 4;
  int s16  = tid & 15;
  const unsigned short* esrc = estripe + (size_t)srow*S + s16*8;
  char* edst = ebuf + srow*EB_STRIDE + s16*16;
  float sinv = linv[srow];
  float* adst = out + 2*OUTSZ + (size_t)bh*S*S + (size_t)(qbase + srow)*S + s16*8;

  // prologue: stage superchunk 0 (+attn), preload superchunk 1
  short8 sA = *(const short8*)(esrc);
  short8 sB = *(const short8*)(esrc + 128);
  *(short8*)(edst)       = sA;
  *(short8*)(edst + 256) = sB;
  wr_attn8(adst,       sA, sinv);
  wr_attn8(adst + 128, sB, sinv);
  sA = *(const short8*)(esrc + 256);
  sB = *(const short8*)(esrc + 384);
  __syncthreads();

  f32x4 acc0 = (f32x4)(0.f), acc1 = (f32x4)(0.f);

  for (int ck = 0; ck < 8; ck++){
    int cur = ck & 1;
    if (ck < 7){
      char* ed = edst + (cur^1)*EB_SZ;
      *(short8*)(ed)       = sA;
      *(short8*)(ed + 256) = sB;
      wr_attn8(adst + (size_t)(ck+1)*256,       sA, sinv);
      wr_attn8(adst + (size_t)(ck+1)*256 + 128, sB, sinv);
    }
    if (ck < 6){
      sA = *(const short8*)(esrc + (size_t)(ck+2)*256);
      sB = *(const short8*)(esrc + (size_t)(ck+2)*256 + 128);
    }
    const char* eb = ebuf + cur*EB_SZ;
    #pragma unroll
    for (int cl = 0; cl < 8; cl++){
      short8 bv = *(const short8*)(vbase + ((size_t)(ck*8 + cl)*64 + lane)*8);
      short8 a0 = *(const short8*)(eb + col*EB_STRIDE + cl*64 + kg*16);
      short8 a1 = *(const short8*)(eb + (16+col)*EB_STRIDE + cl*64 + kg*16);
      acc0 = __builtin_amdgcn_mfma_f32_16x16x32_bf16(a0, bv, acc0, 0, 0, 0);
      acc1 = __builtin_amdgcn_mfma_f32_16x16x32_bf16(a1, bv, acc1, 0, 0, 0);
    }
    __syncthreads();
  }

  float* outp = out + (ri ? OUTSZ : 0) + bhSD;
  #pragma unroll
  for (int r = 0; r < 4; r++){
    int row0 = kg*4 + r;
    outp[(size_t)(qbase + row0) * D + dg*16 + col]      = acc0[r] * linv[row0];
    outp[(size_t)(qbase + 16 + row0) * D + dg*16 + col] = acc1[r] * linv[16 + row0];
  }
}

// ---------------- tier-3: no-workspace fallback (round-2 kernel, proven) ----------
__global__ __launch_bounds__(512) void cattn_kernel(
    const float* __restrict__ q_real, const float* __restrict__ q_imag,
    const float* __restrict__ k_real, const float* __restrict__ k_imag,
    const float* __restrict__ v_real, const float* __restrict__ v_imag,
    const int*   __restrict__ mask,   float* __restrict__ out)
{
  extern __shared__ __align__(16) char lds[];
  float* l_lds = (float*)(lds + (size_t)BQ*S*2);
  float* l_inv = l_lds + 8*BQ;

  int bid = blockIdx.x;
  int swz = (bid & 7) * (NBLK/8) + (bid >> 3);
  int bh    = swz / QT;
  int qt    = swz % QT;
  int b0    = bh / NH;
  int qbase = qt * BQ;

  int tid  = threadIdx.x;
  int w    = tid >> 6;
  int lane = tid & 63;
  int col  = lane & 15;
  int kg   = lane >> 4;

  const size_t bhSD = (size_t)bh * S * D;

  short8 a_r[2][4], a_i[2][4];
  #pragma unroll
  for (int m = 0; m < 2; m++){
    const float* qrp = q_real + bhSD + (size_t)(qbase + m*16 + col) * D;
    const float* qip = q_imag + bhSD + (size_t)(qbase + m*16 + col) * D;
    #pragma unroll
    for (int h = 0; h < 2; h++){
      int d0 = h*32 + kg*8;
      float4 r0 = *(const float4*)(qrp + d0);
      float4 r1 = *(const float4*)(qrp + d0 + 4);
      float4 i0 = *(const float4*)(qip + d0);
      float4 i1 = *(const float4*)(qip + d0 + 4);
      a_r[m][h]   = pack8(r0, r1,  0.125f);
      a_r[m][2+h] = pack8(i0, i1,  0.125f);
      a_i[m][h]   = a_r[m][2+h];
      a_i[m][2+h] = pack8(r0, r1, -0.125f);
    }
  }

  float lsum[2][4] = {{0.f,0.f,0.f,0.f},{0.f,0.f,0.f,0.f}};
  const int* mrow = mask + (size_t)b0 * S * S;

  for (int t = 0; t < 16; t++){
    int key = w*256 + t*16 + col;
    const float* krp = k_real + bhSD + (size_t)key * D;
    const float* kip = k_imag + bhSD + (size_t)key * D;
    short8 bv[4];
    #pragma unroll
    for (int h = 0; h < 2; h++){
      int d0 = h*32 + kg*8;
      float4 r0 = *(const float4*)(krp + d0);
      float4 r1 = *(const float4*)(krp + d0 + 4);
      float4 i0 = *(const float4*)(kip + d0);
      float4 i1 = *(const float4*)(kip + d0 + 4);
      bv[h]   = pack8(r0, r1, 1.f);
      bv[2+h] = pack8(i0, i1, 1.f);
    }
    f32x4 accr[2], acci[2];
    #pragma unroll
    for (int m = 0; m < 2; m++){ accr[m] = (f32x4)(0.f); acci[m] = (f32x4)(0.f); }
    #pragma unroll
    for (int m = 0; m < 2; m++)
      #pragma unroll
      for (int kc = 0; kc < 4; kc++){
        accr[m] = __builtin_amdgcn_mfma_f32_16x16x32_bf16(a_r[m][kc], bv[kc], accr[m], 0, 0, 0);
        acci[m] = __builtin_amdgcn_mfma_f32_16x16x32_bf16(a_i[m][kc], bv[kc], acci[m], 0, 0, 0);
      }
    #pragma unroll
    for (int m = 0; m < 2; m++){
      int qrow_g = qbase + m*16 + kg*4;
      #pragma unroll
      for (int r = 0; r < 4; r++){
        float ar = accr[m][r], ai = acci[m][r];
        float s  = sqrtf(ar*ar + ai*ai);
        int  mv  = mrow[(size_t)(qrow_g + r) * S + key];
        float ex = __expf(s);
        float e  = mv ? ex : 0.f;
        lsum[m][r] += e;
        *(unsigned short*)(lds + eoff(m*16 + kg*4 + r, key)) = f2bf(e);
      }
    }
  }

  #pragma unroll
  for (int m = 0; m < 2; m++)
    #pragma unroll
    for (int r = 0; r < 4; r++){
      float v = lsum[m][r];
      v += __shfl_xor(v, 1); v += __shfl_xor(v, 2);
      v += __shfl_xor(v, 4); v += __shfl_xor(v, 8);
      lsum[m][r] = v;
    }
  if (col == 0){
    #pragma unroll
    for (int m = 0; m < 2; m++)
      #pragma unroll
      for (int r = 0; r < 4; r++)
        l_lds[w*BQ + m*16 + kg*4 + r] = lsum[m][r];
  }
  __syncthreads();
  if (tid < BQ){
    float t = 0.f;
    #pragma unroll
    for (int ww = 0; ww < 8; ww++) t += l_lds[ww*BQ + tid];
    l_inv[tid] = 1.f / t;
  }
  __syncthreads();

  {
    int ri    = w >> 2;
    int dbase = (w & 3) * 16;
    const float* vp = (ri ? v_imag : v_real) + bhSD;
    f32x4 acc[2]; acc[0] = (f32x4)(0.f); acc[1] = (f32x4)(0.f);
    for (int c = 0; c < 64; c++){
      int k0 = c*32 + kg*8;
      short8 bv;
      #pragma unroll
      for (int j = 0; j < 8; j++)
        bv[j] = (short)f2bf(vp[(size_t)(k0 + j) * D + dbase + col]);
      #pragma unroll
      for (int m = 0; m < 2; m++){
        short8 av = *(const short8*)(lds + eoff(m*16 + col, k0));
        acc[m] = __builtin_amdgcn_mfma_f32_16x16x32_bf16(av, bv, acc[m], 0, 0, 0);
      }
    }
    float* outp = out + (ri ? OUTSZ : 0) + bhSD;
    #pragma unroll
    for (int m = 0; m < 2; m++)
      #pragma unroll
      for (int r = 0; r < 4; r++){
        int row = m*16 + kg*4 + r;
        outp[(size_t)(qbase + row) * D + dbase + col] = acc[m][r] * l_inv[row];
      }
  }

  {
    float* attnp = out + 2*OUTSZ + (size_t)bh*S*S + (size_t)qbase*S;
    #pragma unroll
    for (int g = 0; g < 16; g++){
      int flat = g*4096 + tid*8;
      int row  = flat >> 11;
      int k    = flat & 2047;
      short8 ev = *(const short8*)(lds + eoff(row, k));
      float inv = l_inv[row];
      float4 o0, o1;
      o0.x = bf2f((unsigned short)ev[0]) * inv;
      o0.y = bf2f((unsigned short)ev[1]) * inv;
      o0.z = bf2f((unsigned short)ev[2]) * inv;
      o0.w = bf2f((unsigned short)ev[3]) * inv;
      o1.x = bf2f((unsigned short)ev[4]) * inv;
      o1.y = bf2f((unsigned short)ev[5]) * inv;
      o1.z = bf2f((unsigned short)ev[6]) * inv;
      o1.w = bf2f((unsigned short)ev[7]) * inv;
      *(float4*)(attnp + (size_t)row*S + k)     = o0;
      *(float4*)(attnp + (size_t)row*S + k + 4) = o1;
    }
  }
}

extern "C" void kernel_launch(void* const* d_in, const int* in_sizes, int n_in,
                              void* d_out, int out_size, void* d_ws, size_t ws_size,
                              hipStream_t stream)
{
  const float* qr = (const float*)d_in[0];
  const float* qi = (const float*)d_in[1];
  const float* kr = (const float*)d_in[2];
  const float* ki = (const float*)d_in[3];
  const float* vr = (const float*)d_in[4];
  const float* vi = (const float*)d_in[5];
  const int*   mk = (const int*)d_in[6];
  float* out = (float*)d_out;

  if (ws_size >= WS_FULL){
    unsigned short* kf   = (unsigned short*)((char*)d_ws + KF_OFF);
    unsigned short* vf   = (unsigned short*)((char*)d_ws + VF_OFF);
    unsigned*       mq   = (unsigned*)((char*)d_ws + MQ_OFF);
    unsigned short* e_ws = (unsigned short*)((char*)d_ws + E_OFF);
    float*          linv = (float*)((char*)d_ws + LINV_OFF);
    conv_k<<<dim3(3072),     dim3(256), 0, stream>>>(kr, ki, kf);
    conv_v<<<dim3(2*NBH*32), dim3(256), 0, stream>>>(vr, vi, vf);
    conv_m<<<dim3(NB*QT),    dim3(256), 0, stream>>>(mk, mq);
    score_kernel<<<dim3(NBLK), dim3(512), 0, stream>>>(qr, qi, kf, mq, e_ws, linv);
    pv_kernel<<<dim3(NBLK),    dim3(512), 0, stream>>>(e_ws, vf, linv, out);
  } else {
    size_t ldsb = (size_t)BQ*S*2 + (size_t)8*BQ*4 + (size_t)BQ*4;
    cattn_kernel<<<dim3(NBLK), dim3(512), ldsb, stream>>>(qr, qi, kr, ki, vr, vi, mk, out);
  }
}

// Round 9
// 327.542 us; speedup vs baseline: 1.7546x; 1.1363x over previous
//
#include <hip/hip_runtime.h>

#define S     2048
#define D     64
#define NH    12
#define NB    2
#define NBH   (NB*NH)       // 24
#define OUTSZ ((size_t)NBH*S*D)

#define BQ    32
#define QT    (S/BQ)        // 64
#define NBLK  (NBH*QT)      // 1536

// workspace layout (bytes): only converted operands now (no e round-trip)
#define KF_OFF    0
#define KF_SZ     ((size_t)NBH*S*128*2)        // 12582912 (fragment-ordered K)
#define VF_OFF    (KF_OFF + KF_SZ)
#define VF_SZ     ((size_t)2*NBH*D*S*2)        // 12582912 (fragment-ordered V)
#define MQ_OFF    (VF_OFF + VF_SZ)
#define MQ_SZ     ((size_t)NB*QT*S*4)          // 1048576 (32-row bitmasks)
#define WS_NEED   (MQ_OFF + MQ_SZ)             // 26214400

typedef __attribute__((ext_vector_type(8))) short short8;
typedef __attribute__((ext_vector_type(4))) float f32x4;

__device__ __forceinline__ unsigned short f2bf(float x){
  unsigned u = __builtin_bit_cast(unsigned, x);
  u += 0x7fffu + ((u >> 16) & 1u);       // RTNE
  return (unsigned short)(u >> 16);
}
__device__ __forceinline__ float bf2f(unsigned short h){
  unsigned u = ((unsigned)h) << 16;
  return __builtin_bit_cast(float, u);
}
__device__ __forceinline__ short8 pack8(const float4& a, const float4& b, float sc){
  short8 r;
  r[0]=(short)f2bf(a.x*sc); r[1]=(short)f2bf(a.y*sc);
  r[2]=(short)f2bf(a.z*sc); r[3]=(short)f2bf(a.w*sc);
  r[4]=(short)f2bf(b.x*sc); r[5]=(short)f2bf(b.y*sc);
  r[6]=(short)f2bf(b.z*sc); r[7]=(short)f2bf(b.w*sc);
  return r;
}
__device__ __forceinline__ int eoff(int row, int key){
  return ((row << 12) | (key << 1)) ^ ((row & 7) << 4);
}

// ------- conv_k: K -> fragment order kf[bh][grp64][eo2][kc4][lane64][8] -------
__global__ __launch_bounds__(256) void conv_k(const float* __restrict__ kr,
                                              const float* __restrict__ ki,
                                              unsigned short* __restrict__ kf){
  int idx  = blockIdx.x*256 + threadIdx.x;     // 786432 total
  int lane = idx & 63;
  int kc   = (idx >> 6) & 3;
  int eo   = (idx >> 8) & 1;
  int grp  = (idx >> 9) & 63;
  int bh   = idx >> 15;
  int key  = grp*32 + 2*(lane & 15) + eo;
  int d0   = kc*32 + (lane >> 4)*8;
  const float* src = (d0 < 64) ? kr + ((size_t)bh*S + key)*64 + d0
                               : ki + ((size_t)bh*S + key)*64 + (d0 - 64);
  float4 a = *(const float4*)(src);
  float4 b = *(const float4*)(src + 4);
  *(short8*)(kf + (size_t)idx*8) = pack8(a, b, 1.f);
}

// ------- conv_v: V -> fragment order vf[ri*NBH+bh][dg4][c64][lane64][8] -------
__global__ __launch_bounds__(256) void conv_v(const float* __restrict__ vr,
                                              const float* __restrict__ vi,
                                              unsigned short* __restrict__ vf){
  __shared__ unsigned short tile[64][65];      // [d][s_local]
  int bid = blockIdx.x;
  int ri  = bid / (NBH*32);
  int rem = bid % (NBH*32);
  int bh  = rem / 32;
  int s0  = (rem % 32) * 64;
  const float* vp = (ri ? vi : vr) + (size_t)bh*S*D;
  int t = threadIdx.x;
  #pragma unroll
  for (int it = 0; it < 4; it++){
    int row = (t >> 4) + it*16;                // s_local
    int c4  = (t & 15) * 4;                    // d
    float4 v = *(const float4*)(vp + (size_t)(s0+row)*D + c4);
    tile[c4+0][row] = f2bf(v.x);
    tile[c4+1][row] = f2bf(v.y);
    tile[c4+2][row] = f2bf(v.z);
    tile[c4+3][row] = f2bf(v.w);
  }
  __syncthreads();
  unsigned short* dst = vf + (size_t)(ri*NBH + bh) * 4*64*64*8;
  #pragma unroll
  for (int u = 0; u < 2; u++){
    int comb = u*256 + t;                      // 512 combos = dg*2cp*64lane
    int lane = comb & 63;
    int cp   = (comb >> 6) & 1;
    int dg   = comb >> 7;
    int c    = s0/32 + cp;
    int d    = dg*16 + (lane & 15);
    int sl   = cp*32 + (lane >> 4)*8;          // s_local
    short8 o;
    #pragma unroll
    for (int j = 0; j < 8; j++) o[j] = (short)tile[d][sl + j];
    *(short8*)(dst + (((size_t)dg*64 + c)*64 + lane)*8) = o;
  }
}

// ------- conv_m: mask -> mq32[b][qt][key] bitmask of 32 q-rows -------
__global__ __launch_bounds__(256) void conv_m(const int* __restrict__ mask,
                                              unsigned* __restrict__ mq){
  int b  = blockIdx.x >> 6;
  int qt = blockIdx.x & 63;
  int qbase = qt * BQ;
  int t = threadIdx.x;
  #pragma unroll
  for (int it = 0; it < 8; it++){
    int key = it*256 + t;
    unsigned bits = 0;
    #pragma unroll
    for (int j = 0; j < 32; j++)
      bits |= (mask[((size_t)b*S + qbase + j)*S + key] ? 1u : 0u) << j;
    mq[((size_t)b*64 + qt)*S + key] = bits;
  }
}

// ---------------- merged kernel: score+PV+attn, no e workspace ----------------
// Wave w: score role (m = w>>2 half, key-strip g4 = w&3), PV role (ri=w>>2, dg=w&3).
// acci = (qi.kr) - (qr.ki) via two sub-accumulators -> no a_i fragment storage.
#define EB_STRIDE 528
#define EB_SZ     (32*EB_STRIDE)   // 16896 per buffer

__global__ __launch_bounds__(512) void cattn_merged(
    const float* __restrict__ q_real, const float* __restrict__ q_imag,
    const unsigned short* __restrict__ kf,
    const unsigned short* __restrict__ vf,
    const unsigned* __restrict__ mq,
    float* __restrict__ out)
{
  __shared__ __align__(16) char ebuf[2*EB_SZ];
  __shared__ float l_red[8][16];
  __shared__ float linv_lds[BQ];

  int bid = blockIdx.x;
  int swz = (bid & 7) * (NBLK/8) + (bid >> 3);   // XCD-aware, 1536 = 8*192
  int bh    = swz / QT;
  int qt    = swz % QT;
  int b0    = bh / NH;
  int qbase = qt * BQ;

  int tid  = threadIdx.x;
  int w    = tid >> 6;       // 0..7
  int lane = tid & 63;
  int col  = lane & 15;
  int kg   = lane >> 4;

  int m  = w >> 2;           // score row-half / PV ri
  int g4 = w & 3;            // score key-strip / PV dg

  const size_t bhSD = (size_t)bh * S * D;
  const unsigned* mqp = mq + ((size_t)b0*64 + qt) * S;

  // Q fragments (rows qbase + m*16 + col), concat k-dim: kc0,1 = qr; kc2,3 = qi. /8.
  short8 a_r[4];
  {
    const float* qrp = q_real + bhSD + (size_t)(qbase + m*16 + col) * D + kg*8;
    const float* qip = q_imag + bhSD + (size_t)(qbase + m*16 + col) * D + kg*8;
    a_r[0] = pack8(*(const float4*)(qrp),      *(const float4*)(qrp + 4),      0.125f);
    a_r[1] = pack8(*(const float4*)(qrp + 32), *(const float4*)(qrp + 36),     0.125f);
    a_r[2] = pack8(*(const float4*)(qip),      *(const float4*)(qip + 4),      0.125f);
    a_r[3] = pack8(*(const float4*)(qip + 32), *(const float4*)(qip + 36),     0.125f);
  }

  const unsigned short* vbase = vf + ((size_t)(m*NBH + bh)*4 + g4) * 64*64*8;

  float lsum[4] = {0.f, 0.f, 0.f, 0.f};
  f32x4 acc0 = (f32x4)(0.f), acc1 = (f32x4)(0.f);

  // ---------------- Phase 1: per 256-key chunk: score -> LDS -> PV ----------------
  for (int c = 0; c < 8; c++){
    char* eb = ebuf + (c & 1)*EB_SZ;
    #pragma unroll
    for (int gg = 0; gg < 2; gg++){
      int grp = c*8 + g4*2 + gg;               // 32-key group
      const unsigned short* kb = kf + (size_t)(bh*64 + grp) * 2*4*64*8;
      short8 bvA[4], bvB[4];
      #pragma unroll
      for (int kc = 0; kc < 4; kc++){
        bvA[kc] = *(const short8*)(kb + ((size_t)kc*64 + lane)*8);
        bvB[kc] = *(const short8*)(kb + ((size_t)(4+kc)*64 + lane)*8);
      }
      int keyA = grp*32 + 2*col;
      unsigned umA = mqp[keyA];
      unsigned umB = mqp[keyA + 1];

      f32x4 rA=(f32x4)(0.f), pA=(f32x4)(0.f), nA=(f32x4)(0.f);
      f32x4 rB=(f32x4)(0.f), pB=(f32x4)(0.f), nB=(f32x4)(0.f);
      #pragma unroll
      for (int kc = 0; kc < 4; kc++){
        rA = __builtin_amdgcn_mfma_f32_16x16x32_bf16(a_r[kc], bvA[kc], rA, 0, 0, 0);
        rB = __builtin_amdgcn_mfma_f32_16x16x32_bf16(a_r[kc], bvB[kc], rB, 0, 0, 0);
      }
      pA = __builtin_amdgcn_mfma_f32_16x16x32_bf16(a_r[2], bvA[0], pA, 0, 0, 0);
      pA = __builtin_amdgcn_mfma_f32_16x16x32_bf16(a_r[3], bvA[1], pA, 0, 0, 0);
      nA = __builtin_amdgcn_mfma_f32_16x16x32_bf16(a_r[0], bvA[2], nA, 0, 0, 0);
      nA = __builtin_amdgcn_mfma_f32_16x16x32_bf16(a_r[1], bvA[3], nA, 0, 0, 0);
      pB = __builtin_amdgcn_mfma_f32_16x16x32_bf16(a_r[2], bvB[0], pB, 0, 0, 0);
      pB = __builtin_amdgcn_mfma_f32_16x16x32_bf16(a_r[3], bvB[1], pB, 0, 0, 0);
      nB = __builtin_amdgcn_mfma_f32_16x16x32_bf16(a_r[0], bvB[2], nB, 0, 0, 0);
      nB = __builtin_amdgcn_mfma_f32_16x16x32_bf16(a_r[1], bvB[3], nB, 0, 0, 0);

      int keyL = (g4*2 + gg)*32 + 2*col;       // local key within chunk
      #pragma unroll
      for (int r = 0; r < 4; r++){
        int rowl = kg*4 + r;
        int rowg = m*16 + rowl;
        float iA = pA[r] - nA[r];
        float sA = sqrtf(rA[r]*rA[r] + iA*iA);
        float eA = ((umA >> rowg) & 1u) ? __expf(sA) : 0.f;
        float iB = pB[r] - nB[r];
        float sB = sqrtf(rB[r]*rB[r] + iB*iB);
        float eB = ((umB >> rowg) & 1u) ? __expf(sB) : 0.f;
        lsum[r] += eA + eB;
        unsigned pk = (unsigned)f2bf(eA) | ((unsigned)f2bf(eB) << 16);
        *(unsigned*)(eb + rowg*EB_STRIDE + keyL*2) = pk;
      }
    }
    __syncthreads();
    // PV on this chunk: ri = m, dg = g4
    #pragma unroll
    for (int cl = 0; cl < 8; cl++){
      short8 bv = *(const short8*)(vbase + ((size_t)(c*8 + cl)*64 + lane)*8);
      short8 a0 = *(const short8*)(eb + col*EB_STRIDE + cl*64 + kg*16);
      short8 a1 = *(const short8*)(eb + (16+col)*EB_STRIDE + cl*64 + kg*16);
      acc0 = __builtin_amdgcn_mfma_f32_16x16x32_bf16(a0, bv, acc0, 0, 0, 0);
      acc1 = __builtin_amdgcn_mfma_f32_16x16x32_bf16(a1, bv, acc1, 0, 0, 0);
    }
  }

  // ---------------- row-sum reduce -> linv ----------------
  #pragma unroll
  for (int r = 0; r < 4; r++){
    float v = lsum[r];
    v += __shfl_xor(v, 1); v += __shfl_xor(v, 2);
    v += __shfl_xor(v, 4); v += __shfl_xor(v, 8);
    if (col == 0) l_red[w][kg*4 + r] = v;
  }
  __syncthreads();
  if (tid < BQ){
    int mm = tid >> 4, lr = tid & 15;
    float t = l_red[4*mm][lr] + l_red[4*mm+1][lr] + l_red[4*mm+2][lr] + l_red[4*mm+3][lr];
    linv_lds[tid] = 1.f / t;
  }
  __syncthreads();

  // ---------------- out write (PV epilogue) ----------------
  {
    float* outp = out + (m ? OUTSZ : 0) + bhSD;
    #pragma unroll
    for (int r = 0; r < 4; r++){
      int row0 = kg*4 + r;
      outp[(size_t)(qbase + row0) * D + g4*16 + col]      = acc0[r] * linv_lds[row0];
      outp[(size_t)(qbase + 16 + row0) * D + g4*16 + col] = acc1[r] * linv_lds[16 + row0];
    }
  }

  // ---------------- Phase 2: recompute scores, write attn = e * linv ----------------
  float linv_l[4];
  #pragma unroll
  for (int r = 0; r < 4; r++) linv_l[r] = linv_lds[m*16 + kg*4 + r];

  float* attnp = out + 2*OUTSZ + (size_t)bh*S*S + (size_t)qbase*S;

  for (int c = 0; c < 8; c++){
    #pragma unroll
    for (int gg = 0; gg < 2; gg++){
      int grp = c*8 + g4*2 + gg;
      const unsigned short* kb = kf + (size_t)(bh*64 + grp) * 2*4*64*8;
      short8 bvA[4], bvB[4];
      #pragma unroll
      for (int kc = 0; kc < 4; kc++){
        bvA[kc] = *(const short8*)(kb + ((size_t)kc*64 + lane)*8);
        bvB[kc] = *(const short8*)(kb + ((size_t)(4+kc)*64 + lane)*8);
      }
      int keyA = grp*32 + 2*col;
      unsigned umA = mqp[keyA];
      unsigned umB = mqp[keyA + 1];

      f32x4 rA=(f32x4)(0.f), pA=(f32x4)(0.f), nA=(f32x4)(0.f);
      f32x4 rB=(f32x4)(0.f), pB=(f32x4)(0.f), nB=(f32x4)(0.f);
      #pragma unroll
      for (int kc = 0; kc < 4; kc++){
        rA = __builtin_amdgcn_mfma_f32_16x16x32_bf16(a_r[kc], bvA[kc], rA, 0, 0, 0);
        rB = __builtin_amdgcn_mfma_f32_16x16x32_bf16(a_r[kc], bvB[kc], rB, 0, 0, 0);
      }
      pA = __builtin_amdgcn_mfma_f32_16x16x32_bf16(a_r[2], bvA[0], pA, 0, 0, 0);
      pA = __builtin_amdgcn_mfma_f32_16x16x32_bf16(a_r[3], bvA[1], pA, 0, 0, 0);
      nA = __builtin_amdgcn_mfma_f32_16x16x32_bf16(a_r[0], bvA[2], nA, 0, 0, 0);
      nA = __builtin_amdgcn_mfma_f32_16x16x32_bf16(a_r[1], bvA[3], nA, 0, 0, 0);
      pB = __builtin_amdgcn_mfma_f32_16x16x32_bf16(a_r[2], bvB[0], pB, 0, 0, 0);
      pB = __builtin_amdgcn_mfma_f32_16x16x32_bf16(a_r[3], bvB[1], pB, 0, 0, 0);
      nB = __builtin_amdgcn_mfma_f32_16x16x32_bf16(a_r[0], bvB[2], nB, 0, 0, 0);
      nB = __builtin_amdgcn_mfma_f32_16x16x32_bf16(a_r[1], bvB[3], nB, 0, 0, 0);

      #pragma unroll
      for (int r = 0; r < 4; r++){
        int rowg = m*16 + kg*4 + r;
        float iA = pA[r] - nA[r];
        float sA = sqrtf(rA[r]*rA[r] + iA*iA);
        float eA = ((umA >> rowg) & 1u) ? __expf(sA) : 0.f;
        float iB = pB[r] - nB[r];
        float sB = sqrtf(rB[r]*rB[r] + iB*iB);
        float eB = ((umB >> rowg) & 1u) ? __expf(sB) : 0.f;
        float2 o; o.x = eA * linv_l[r]; o.y = eB * linv_l[r];
        *(float2*)(attnp + (size_t)rowg*S + keyA) = o;
      }
    }
  }
}

// ---------------- tier-3: no-workspace fallback (round-2 kernel, proven) ----------
__global__ __launch_bounds__(512) void cattn_kernel(
    const float* __restrict__ q_real, const float* __restrict__ q_imag,
    const float* __restrict__ k_real, const float* __restrict__ k_imag,
    const float* __restrict__ v_real, const float* __restrict__ v_imag,
    const int*   __restrict__ mask,   float* __restrict__ out)
{
  extern __shared__ __align__(16) char lds[];
  float* l_lds = (float*)(lds + (size_t)BQ*S*2);
  float* l_inv = l_lds + 8*BQ;

  int bid = blockIdx.x;
  int swz = (bid & 7) * (NBLK/8) + (bid >> 3);
  int bh    = swz / QT;
  int qt    = swz % QT;
  int b0    = bh / NH;
  int qbase = qt * BQ;

  int tid  = threadIdx.x;
  int w    = tid >> 6;
  int lane = tid & 63;
  int col  = lane & 15;
  int kg   = lane >> 4;

  const size_t bhSD = (size_t)bh * S * D;

  short8 a_r[2][4], a_i[2][4];
  #pragma unroll
  for (int m = 0; m < 2; m++){
    const float* qrp = q_real + bhSD + (size_t)(qbase + m*16 + col) * D;
    const float* qip = q_imag + bhSD + (size_t)(qbase + m*16 + col) * D;
    #pragma unroll
    for (int h = 0; h < 2; h++){
      int d0 = h*32 + kg*8;
      float4 r0 = *(const float4*)(qrp + d0);
      float4 r1 = *(const float4*)(qrp + d0 + 4);
      float4 i0 = *(const float4*)(qip + d0);
      float4 i1 = *(const float4*)(qip + d0 + 4);
      a_r[m][h]   = pack8(r0, r1,  0.125f);
      a_r[m][2+h] = pack8(i0, i1,  0.125f);
      a_i[m][h]   = a_r[m][2+h];
      a_i[m][2+h] = pack8(r0, r1, -0.125f);
    }
  }

  float lsum[2][4] = {{0.f,0.f,0.f,0.f},{0.f,0.f,0.f,0.f}};
  const int* mrow = mask + (size_t)b0 * S * S;

  for (int t = 0; t < 16; t++){
    int key = w*256 + t*16 + col;
    const float* krp = k_real + bhSD + (size_t)key * D;
    const float* kip = k_imag + bhSD + (size_t)key * D;
    short8 bv[4];
    #pragma unroll
    for (int h = 0; h < 2; h++){
      int d0 = h*32 + kg*8;
      float4 r0 = *(const float4*)(krp + d0);
      float4 r1 = *(const float4*)(krp + d0 + 4);
      float4 i0 = *(const float4*)(kip + d0);
      float4 i1 = *(const float4*)(kip + d0 + 4);
      bv[h]   = pack8(r0, r1, 1.f);
      bv[2+h] = pack8(i0, i1, 1.f);
    }
    f32x4 accr[2], acci[2];
    #pragma unroll
    for (int m = 0; m < 2; m++){ accr[m] = (f32x4)(0.f); acci[m] = (f32x4)(0.f); }
    #pragma unroll
    for (int m = 0; m < 2; m++)
      #pragma unroll
      for (int kc = 0; kc < 4; kc++){
        accr[m] = __builtin_amdgcn_mfma_f32_16x16x32_bf16(a_r[m][kc], bv[kc], accr[m], 0, 0, 0);
        acci[m] = __builtin_amdgcn_mfma_f32_16x16x32_bf16(a_i[m][kc], bv[kc], acci[m], 0, 0, 0);
      }
    #pragma unroll
    for (int m = 0; m < 2; m++){
      int qrow_g = qbase + m*16 + kg*4;
      #pragma unroll
      for (int r = 0; r < 4; r++){
        float ar = accr[m][r], ai = acci[m][r];
        float s  = sqrtf(ar*ar + ai*ai);
        int  mv  = mrow[(size_t)(qrow_g + r) * S + key];
        float ex = __expf(s);
        float e  = mv ? ex : 0.f;
        lsum[m][r] += e;
        *(unsigned short*)(lds + eoff(m*16 + kg*4 + r, key)) = f2bf(e);
      }
    }
  }

  #pragma unroll
  for (int m = 0; m < 2; m++)
    #pragma unroll
    for (int r = 0; r < 4; r++){
      float v = lsum[m][r];
      v += __shfl_xor(v, 1); v += __shfl_xor(v, 2);
      v += __shfl_xor(v, 4); v += __shfl_xor(v, 8);
      lsum[m][r] = v;
    }
  if (col == 0){
    #pragma unroll
    for (int m = 0; m < 2; m++)
      #pragma unroll
      for (int r = 0; r < 4; r++)
        l_lds[w*BQ + m*16 + kg*4 + r] = lsum[m][r];
  }
  __syncthreads();
  if (tid < BQ){
    float t = 0.f;
    #pragma unroll
    for (int ww = 0; ww < 8; ww++) t += l_lds[ww*BQ + tid];
    l_inv[tid] = 1.f / t;
  }
  __syncthreads();

  {
    int ri    = w >> 2;
    int dbase = (w & 3) * 16;
    const float* vp = (ri ? v_imag : v_real) + bhSD;
    f32x4 acc[2]; acc[0] = (f32x4)(0.f); acc[1] = (f32x4)(0.f);
    for (int c = 0; c < 64; c++){
      int k0 = c*32 + kg*8;
      short8 bv;
      #pragma unroll
      for (int j = 0; j < 8; j++)
        bv[j] = (short)f2bf(vp[(size_t)(k0 + j) * D + dbase + col]);
      #pragma unroll
      for (int m = 0; m < 2; m++){
        short8 av = *(const short8*)(lds + eoff(m*16 + col, k0));
        acc[m] = __builtin_amdgcn_mfma_f32_16x16x32_bf16(av, bv, acc[m], 0, 0, 0);
      }
    }
    float* outp = out + (ri ? OUTSZ : 0) + bhSD;
    #pragma unroll
    for (int m = 0; m < 2; m++)
      #pragma unroll
      for (int r = 0; r < 4; r++){
        int row = m*16 + kg*4 + r;
        outp[(size_t)(qbase + row) * D + dbase + col] = acc[m][r] * l_inv[row];
      }
  }

  {
    float* attnp = out + 2*OUTSZ + (size_t)bh*S*S + (size_t)qbase*S;
    #pragma unroll
    for (int g = 0; g < 16; g++){
      int flat = g*4096 + tid*8;
      int row  = flat >> 11;
      int k    = flat & 2047;
      short8 ev = *(const short8*)(lds + eoff(row, k));
      float inv = l_inv[row];
      float4 o0, o1;
      o0.x = bf2f((unsigned short)ev[0]) * inv;
      o0.y = bf2f((unsigned short)ev[1]) * inv;
      o0.z = bf2f((unsigned short)ev[2]) * inv;
      o0.w = bf2f((unsigned short)ev[3]) * inv;
      o1.x = bf2f((unsigned short)ev[4]) * inv;
      o1.y = bf2f((unsigned short)ev[5]) * inv;
      o1.z = bf2f((unsigned short)ev[6]) * inv;
      o1.w = bf2f((unsigned short)ev[7]) * inv;
      *(float4*)(attnp + (size_t)row*S + k)     = o0;
      *(float4*)(attnp + (size_t)row*S + k + 4) = o1;
    }
  }
}

extern "C" void kernel_launch(void* const* d_in, const int* in_sizes, int n_in,
                              void* d_out, int out_size, void* d_ws, size_t ws_size,
                              hipStream_t stream)
{
  const float* qr = (const float*)d_in[0];
  const float* qi = (const float*)d_in[1];
  const float* kr = (const float*)d_in[2];
  const float* ki = (const float*)d_in[3];
  const float* vr = (const float*)d_in[4];
  const float* vi = (const float*)d_in[5];
  const int*   mk = (const int*)d_in[6];
  float* out = (float*)d_out;

  if (ws_size >= WS_NEED){
    unsigned short* kf = (unsigned short*)((char*)d_ws + KF_OFF);
    unsigned short* vf = (unsigned short*)((char*)d_ws + VF_OFF);
    unsigned*       mq = (unsigned*)((char*)d_ws + MQ_OFF);
    conv_k<<<dim3(3072),     dim3(256), 0, stream>>>(kr, ki, kf);
    conv_v<<<dim3(2*NBH*32), dim3(256), 0, stream>>>(vr, vi, vf);
    conv_m<<<dim3(NB*QT),    dim3(256), 0, stream>>>(mk, mq);
    cattn_merged<<<dim3(NBLK), dim3(512), 0, stream>>>(qr, qi, kf, vf, mq, out);
  } else {
    size_t ldsb = (size_t)BQ*S*2 + (size_t)8*BQ*4 + (size_t)BQ*4;
    cattn_kernel<<<dim3(NBLK), dim3(512), ldsb, stream>>>(qr, qi, kr, ki, vr, vi, mk, out);
  }
}